// Round 4
// baseline (2470.133 us; speedup 1.0000x reference)
//
#include <hip/hip_runtime.h>
#include <math.h>

typedef unsigned int u32;
typedef unsigned short u16;
typedef __attribute__((ext_vector_type(8))) short bf16x8;
typedef __attribute__((ext_vector_type(4))) float f32x4;

#define E_TOT 100000
#define ET 16
constexpr int DIM = 320;

constexpr float SC_S_SCALE = 0.022097086912079608f;  // 1/sqrt(128*16)
constexpr float SC_V_SCALE = 0.03125f;               // 1/32
constexpr float INV_SQRT128 = 0.08838834764831845f;
constexpr float INV_8 = 0.125f;
constexpr float INV_S384 = 0.05103103630798288f;     // 1/sqrt(384)
constexpr float INV_24 = 0.041666666666666664f;      // 1/sqrt(576)
constexpr float INV_S192 = 0.07216878364870323f;     // 1/sqrt(192)
constexpr float RSQRT2 = 0.7071067811865476f;

// element offsets in bf16 weight arena (in d_ws)
#define OW_W2S   0        /* [128 u][2048 k=s*128+v]        */
#define OW_SCV   262144   /* [192 u'][3072 k=s*192+(3v+m')] */
#define OW_PRE0  851968   /* [128][128]  */
#define OW_PRE1X 868352   /* [192][192] block-diag */
#define OW_SS    905216   /* [192][384]  */
#define OW_VS    978944   /* [192][192]  */
#define OW_SV    1015808  /* [64][384]   */
#define OW_VVX   1040384  /* [192][576] block-diag */
#define OW_F1    1150976  /* [64][128]   */
#define OW_F2    1159168  /* [64][64]    */
#define OW_F3    1163264  /* [192][64]   */
#define OW_P0    1175552  /* [128][128]  */
#define OW_P1X   1191936  /* [192][192] block-diag */
#define OW_END   1228800

__device__ __forceinline__ float sigmoidf_(float x) { return 1.0f / (1.0f + __expf(-x)); }
__device__ __forceinline__ float siluf_(float x) { return x * sigmoidf_(x); }
__device__ __forceinline__ float bf2f(u16 h) {
  u32 u = ((u32)h) << 16;
  return __builtin_bit_cast(float, u);
}
__device__ __forceinline__ u16 f2bf(float f) {
  u32 u = __builtin_bit_cast(u32, f);
  return (u16)((u + 0x7fffu + ((u >> 16) & 1u)) >> 16);
}
__device__ __forceinline__ bf16x8 pack8(float4 r0, float4 r1, float s) {
  bf16x8 a;
  a[0] = (short)f2bf(r0.x * s); a[1] = (short)f2bf(r0.y * s);
  a[2] = (short)f2bf(r0.z * s); a[3] = (short)f2bf(r0.w * s);
  a[4] = (short)f2bf(r1.x * s); a[5] = (short)f2bf(r1.y * s);
  a[6] = (short)f2bf(r1.z * s); a[7] = (short)f2bf(r1.w * s);
  return a;
}
__device__ __forceinline__ bf16x8 scale8(bf16x8 v, float s) {
  bf16x8 r;
  #pragma unroll
  for (int j = 0; j < 8; ++j) r[j] = (short)f2bf(bf2f((u16)v[j]) * s);
  return r;
}
// swizzled bf16 LDS helpers (XOR byte bits 4-6 with row&7); rowB multiple of 128
__device__ __forceinline__ void stb(char* base, int row, int rowB, int colByte, u16 v) {
  *(u16*)(base + row * rowB + (colByte ^ ((row & 7) << 4))) = v;
}
__device__ __forceinline__ u16 ldbs(const char* base, int row, int rowB, int colByte) {
  return *(const u16*)(base + row * rowB + (colByte ^ ((row & 7) << 4)));
}
__device__ __forceinline__ bf16x8 ldb8(const char* base, int row, int rowB, int colByte) {
  return *(const bf16x8*)(base + row * rowB + (colByte ^ ((row & 7) << 4)));
}

// ---------------- K0: weight prep (transpose + expand + fold scales) ----------------
__global__ __launch_bounds__(256) void k_prep(
    const float* __restrict__ Wsc_s, const float* __restrict__ Wsc_v,
    const float* __restrict__ Wpre0, const float* __restrict__ Wpre1,
    const float* __restrict__ Wss, const float* __restrict__ Wvs,
    const float* __restrict__ Wsv, const float* __restrict__ Wvv,
    const float* __restrict__ Wf1, const float* __restrict__ Wf2,
    const float* __restrict__ Wf3, const float* __restrict__ Wpost0,
    const float* __restrict__ Wpost1, u16* __restrict__ dst) {
  int o = blockIdx.x * 256 + threadIdx.x;
  if (o >= OW_END) return;
  float val;
  if (o < OW_SCV) {
    int u = o >> 11, k = o & 2047, s = k >> 7, v = k & 127;
    val = Wsc_s[((size_t)(v * 16 + s)) * 128 + u] * SC_S_SCALE;
  } else if (o < OW_PRE0) {
    int oo = o - OW_SCV;
    int up = oo / 3072, k = oo % 3072, s = k / 192, r = k % 192;
    int vv = r / 3, mp = r % 3, u = up / 3, m = up % 3;
    val = (mp == m) ? Wsc_v[((size_t)(vv * 16 + s)) * 64 + u] * SC_V_SCALE : 0.f;
  } else if (o < OW_PRE1X) {
    int oo = o - OW_PRE0; int u = oo >> 7, k = oo & 127;
    val = Wpre0[k * 128 + u] * INV_SQRT128;
  } else if (o < OW_SS) {
    int oo = o - OW_PRE1X;
    int up = oo / 192, kp = oo % 192, vv = kp / 3, mp = kp % 3, u = up / 3, m = up % 3;
    val = (mp == m) ? Wpre1[vv * 64 + u] * INV_8 : 0.f;
  } else if (o < OW_VS) {
    int oo = o - OW_SS; int u = oo / 384, k = oo % 384;
    val = Wss[k * 192 + u] * (INV_S384 * RSQRT2);
  } else if (o < OW_SV) {
    int oo = o - OW_VS; int u = oo / 192, k = oo % 192;
    val = Wvs[k * 192 + u] * (INV_24 * RSQRT2);
  } else if (o < OW_VVX) {
    int oo = o - OW_SV; int u = oo / 384, k = oo % 384;
    val = Wsv[k * 64 + u] * (INV_S384 * RSQRT2);
  } else if (o < OW_F1) {
    int oo = o - OW_VVX;
    int up = oo / 576, k = oo % 576, src = k / 192, r = k % 192;
    int vv = r / 3, mp = r % 3, u = up / 3, m = up % 3;
    val = (mp == m) ? Wvv[(src * 64 + vv) * 64 + u] * (INV_S192 * RSQRT2) : 0.f;
  } else if (o < OW_F2) {
    int oo = o - OW_F1; int u = oo >> 7, k = oo & 127;
    val = Wf1[k * 64 + u];
  } else if (o < OW_F3) {
    int oo = o - OW_F2; int u = oo >> 6, k = oo & 63;
    val = Wf2[k * 64 + u];
  } else if (o < OW_P0) {
    int oo = o - OW_F3; int u = oo >> 6, k = oo & 63;
    val = Wf3[k * 192 + u];
  } else if (o < OW_P1X) {
    int oo = o - OW_P0; int u = oo >> 7, k = oo & 127;
    val = Wpost0[k * 128 + u] * INV_SQRT128;
  } else {
    int oo = o - OW_P1X;
    int up = oo / 192, kp = oo % 192, vv = kp / 3, mp = kp % 3, u = up / 3, m = up % 3;
    val = (mp == m) ? Wpost1[vv * 64 + u] * INV_8 : 0.f;
  }
  dst[o] = f2bf(val);
}

// ---------------- K1a: sc_s — zero-LDS, barrier-free MFMA ----------------
__global__ __launch_bounds__(256, 4) void k_sc_s(
    const float* __restrict__ edge_fea, const float* __restrict__ ohp,
    const u16* __restrict__ W2s, float* __restrict__ out) {
  const int t = threadIdx.x, lane = t & 63;
  const int mt = t >> 6, l15 = lane & 15, q8 = lane >> 4, q4 = q8 << 2;
  const int e0 = blockIdx.x * 64;
  const int eA = e0 + mt * 16 + l15;
  const bool okA = eA < E_TOT;
  const float* arow = edge_fea + (size_t)eA * DIM;
  const float* ohrow = ohp + (size_t)eA * 16;
  const u16* bp = W2s + (size_t)l15 * 2048 + q8 * 8;
  f32x4 acc[8];
  #pragma unroll
  for (int i = 0; i < 8; ++i) acc[i] = (f32x4){0.f, 0.f, 0.f, 0.f};
  #pragma unroll
  for (int kc = 0; kc < 4; ++kc) {
    float4 r0 = okA ? *(const float4*)(arow + kc * 32 + q8 * 8) : make_float4(0, 0, 0, 0);
    float4 r1 = okA ? *(const float4*)(arow + kc * 32 + q8 * 8 + 4) : make_float4(0, 0, 0, 0);
    for (int s = 0; s < 16; ++s) {
      float oh = okA ? ohrow[s] : 0.f;
      bf16x8 a = pack8(r0, r1, oh);
      const u16* bk = bp + s * 128 + kc * 32;
      #pragma unroll
      for (int nt = 0; nt < 8; ++nt) {
        bf16x8 b = *(const bf16x8*)(bk + (size_t)nt * (16 * 2048));
        acc[nt] = __builtin_amdgcn_mfma_f32_16x16x32_bf16(a, b, acc[nt], 0, 0, 0);
      }
    }
  }
  #pragma unroll
  for (int nt = 0; nt < 8; ++nt) {
    int u = nt * 16 + l15;
    #pragma unroll
    for (int j = 0; j < 4; ++j) {
      int e = e0 + mt * 16 + q4 + j;
      if (e < E_TOT) out[(size_t)e * DIM + u] = acc[nt][j];
    }
  }
}

// ---------------- K1b: sc_v — interleaved block-diag, zero-LDS ----------------
__global__ __launch_bounds__(256, 4) void k_sc_v(
    const float* __restrict__ edge_fea, const float* __restrict__ ohp,
    const u16* __restrict__ WscvX, float* __restrict__ out) {
  const int t = threadIdx.x, lane = t & 63;
  const int mt = t >> 6, l15 = lane & 15, q8 = lane >> 4, q4 = q8 << 2;
  const int e0 = blockIdx.x * 64;
  const int eA = e0 + mt * 16 + l15;
  const bool okA = eA < E_TOT;
  const float* arow = edge_fea + (size_t)eA * DIM + 128;
  const float* ohrow = ohp + (size_t)eA * 16;
  const u16* bp = WscvX + (size_t)l15 * 3072 + q8 * 8;
  f32x4 acc[12];
  #pragma unroll
  for (int i = 0; i < 12; ++i) acc[i] = (f32x4){0.f, 0.f, 0.f, 0.f};
  #pragma unroll
  for (int kc = 0; kc < 6; ++kc) {
    float4 r0 = okA ? *(const float4*)(arow + kc * 32 + q8 * 8) : make_float4(0, 0, 0, 0);
    float4 r1 = okA ? *(const float4*)(arow + kc * 32 + q8 * 8 + 4) : make_float4(0, 0, 0, 0);
    for (int s = 0; s < 16; ++s) {
      float oh = okA ? ohrow[s] : 0.f;
      bf16x8 a = pack8(r0, r1, oh);
      const u16* bk = bp + s * 192 + kc * 32;
      #pragma unroll
      for (int nt = 0; nt < 12; ++nt) {
        bf16x8 b = *(const bf16x8*)(bk + (size_t)nt * (16 * 3072));
        acc[nt] = __builtin_amdgcn_mfma_f32_16x16x32_bf16(a, b, acc[nt], 0, 0, 0);
      }
    }
  }
  #pragma unroll
  for (int nt = 0; nt < 12; ++nt) {
    int up = nt * 16 + l15;
    #pragma unroll
    for (int j = 0; j < 4; ++j) {
      int e = e0 + mt * 16 + q4 + j;
      if (e < E_TOT) out[(size_t)e * DIM + 128 + up] = acc[nt][j];
    }
  }
}

// ---------------- K2: fused chain (pre + mix + MLP + gate + post), M=32 ----------------
__global__ __launch_bounds__(512, 4) void k_chain(
    const float* __restrict__ node_fea, const float* __restrict__ edge_sh,
    const float* __restrict__ edge_fea, const float* __restrict__ elen,
    const int* __restrict__ eidx, const u16* __restrict__ wbf,
    const float* __restrict__ bpre0, const float* __restrict__ bf1,
    const float* __restrict__ bf2, const float* __restrict__ bf3,
    const float* __restrict__ bpost0, float* __restrict__ out) {
  __shared__ float shF[32][4];
  __shared__ int ijL[2][32];
  __shared__ char Ds[32 * 256];    // s
  __shared__ char Ev[32 * 384];    // v (interleaved)
  __shared__ char svhB[32 * 384];  // aliased by zvB after BAR3b
  __shared__ char t1B[32 * 128];
  __shared__ char h1B[32 * 128];
  __shared__ char h2B[32 * 128];
  __shared__ char wB[32 * 384];
  __shared__ char zsB[32 * 256];
  __shared__ char gateB[32 * 128];
  char* zvB = svhB;

  const int t = threadIdx.x, lane = t & 63;
  const int wv = t >> 6, mt2 = wv >> 2, wn = wv & 3;
  const int l15 = lane & 15, q8 = lane >> 4, q4 = q8 << 2, cbl = q8 << 4;
  const int e0 = blockIdx.x * 32;
  const int eA = mt2 * 16 + l15;

  if (t < 32) ijL[0][t] = eidx[e0 + t];
  else if (t < 64) ijL[1][t - 32] = eidx[E_TOT + e0 + t - 32];
  if (t < 128) { int e = t >> 2, m = t & 3; shF[e][m] = edge_sh[(size_t)(e0 + e) * 4 + m]; }
  __syncthreads();

  const u16* Wpre0T  = wbf + OW_PRE0;
  const u16* Wpre1X  = wbf + OW_PRE1X;
  const u16* WssT    = wbf + OW_SS;
  const u16* WvsT    = wbf + OW_VS;
  const u16* WsvT    = wbf + OW_SV;
  const u16* WvvX    = wbf + OW_VVX;
  const u16* Wf1T    = wbf + OW_F1;
  const u16* Wf2T    = wbf + OW_F2;
  const u16* Wf3T    = wbf + OW_F3;
  const u16* Wpost0T = wbf + OW_P0;
  const u16* Wpost1X = wbf + OW_P1X;

  // ---- h1 = silu(elen@Wf1 + b), 1 acc ----
  {
    f32x4 acc = (f32x4){0.f, 0.f, 0.f, 0.f};
    const float* ar = elen + (size_t)(e0 + eA) * 128;
    #pragma unroll
    for (int kc = 0; kc < 4; ++kc) {
      float4 r0 = *(const float4*)(ar + kc * 32 + q8 * 8);
      float4 r1 = *(const float4*)(ar + kc * 32 + q8 * 8 + 4);
      bf16x8 a = pack8(r0, r1, 1.f);
      bf16x8 b = *(const bf16x8*)(Wf1T + (size_t)(wn * 16 + l15) * 128 + kc * 32 + q8 * 8);
      acc = __builtin_amdgcn_mfma_f32_16x16x32_bf16(a, b, acc, 0, 0, 0);
    }
    int u = wn * 16 + l15;
    float bias = bf1[u];
    #pragma unroll
    for (int j = 0; j < 4; ++j)
      stb(h1B, mt2 * 16 + q4 + j, 128, u * 2, f2bf(siluf_(acc[j] + bias)));
  }
  // ---- P1s: s = es@Wpre0' + b, 2 acc ----
  {
    f32x4 acc[2] = {(f32x4){0,0,0,0}, (f32x4){0,0,0,0}};
    const float* ar = edge_fea + (size_t)(e0 + eA) * DIM;
    #pragma unroll
    for (int kc = 0; kc < 4; ++kc) {
      float4 r0 = *(const float4*)(ar + kc * 32 + q8 * 8);
      float4 r1 = *(const float4*)(ar + kc * 32 + q8 * 8 + 4);
      bf16x8 a = pack8(r0, r1, 1.f);
      #pragma unroll
      for (int i = 0; i < 2; ++i) {
        int u = (wn * 2 + i) * 16 + l15;
        bf16x8 b = *(const bf16x8*)(Wpre0T + (size_t)u * 128 + kc * 32 + q8 * 8);
        acc[i] = __builtin_amdgcn_mfma_f32_16x16x32_bf16(a, b, acc[i], 0, 0, 0);
      }
    }
    #pragma unroll
    for (int i = 0; i < 2; ++i) {
      int u = (wn * 2 + i) * 16 + l15;
      float bias = bpre0[u];
      #pragma unroll
      for (int j = 0; j < 4; ++j)
        stb(Ds, mt2 * 16 + q4 + j, 256, u * 2, f2bf(acc[i][j] + bias));
    }
  }
  // ---- P1v: v = ev@Wpre1X, 3 acc ----
  {
    f32x4 acc[3] = {(f32x4){0,0,0,0}, (f32x4){0,0,0,0}, (f32x4){0,0,0,0}};
    const float* ar = edge_fea + (size_t)(e0 + eA) * DIM + 128;
    #pragma unroll
    for (int kc = 0; kc < 6; ++kc) {
      float4 r0 = *(const float4*)(ar + kc * 32 + q8 * 8);
      float4 r1 = *(const float4*)(ar + kc * 32 + q8 * 8 + 4);
      bf16x8 a = pack8(r0, r1, 1.f);
      #pragma unroll
      for (int i = 0; i < 3; ++i) {
        int up = (wn * 3 + i) * 16 + l15;
        bf16x8 b = *(const bf16x8*)(Wpre1X + (size_t)up * 192 + kc * 32 + q8 * 8);
        acc[i] = __builtin_amdgcn_mfma_f32_16x16x32_bf16(a, b, acc[i], 0, 0, 0);
      }
    }
    #pragma unroll
    for (int i = 0; i < 3; ++i) {
      int up = (wn * 3 + i) * 16 + l15;
      #pragma unroll
      for (int j = 0; j < 4; ++j)
        stb(Ev, mt2 * 16 + q4 + j, 384, up * 2, f2bf(acc[i][j]));
    }
  }
  __syncthreads();  // BAR1: h1, s, v ready

  // ---- h2 = silu(h1@Wf2 + b), 1 acc ----
  {
    f32x4 acc = (f32x4){0.f, 0.f, 0.f, 0.f};
    #pragma unroll
    for (int kc = 0; kc < 2; ++kc) {
      bf16x8 a = ldb8(h1B, eA, 128, kc * 64 + cbl);
      bf16x8 b = *(const bf16x8*)(Wf2T + (size_t)(wn * 16 + l15) * 64 + kc * 32 + q8 * 8);
      acc = __builtin_amdgcn_mfma_f32_16x16x32_bf16(a, b, acc, 0, 0, 0);
    }
    int u = wn * 16 + l15;
    float bias = bf2[u];
    #pragma unroll
    for (int j = 0; j < 4; ++j)
      stb(h2B, mt2 * 16 + q4 + j, 128, u * 2, f2bf(siluf_(acc[j] + bias)));
  }
  // ---- svh[e][K] = sum_m v_in[e,K,m]*sh1[m] ----
  for (int o = t; o < 32 * 192; o += 512) {
    int e = o / 192, K = o % 192;
    int src = K >> 6, kk = K & 63;
    float x0, x1, x2;
    if (src < 2) {
      const float* np = node_fea + (size_t)ijL[src][e] * DIM + 128 + 3 * kk;
      x0 = np[0]; x1 = np[1]; x2 = np[2];
    } else {
      x0 = bf2f(ldbs(Ev, e, 384, 6 * kk));
      x1 = bf2f(ldbs(Ev, e, 384, 6 * kk + 2));
      x2 = bf2f(ldbs(Ev, e, 384, 6 * kk + 4));
    }
    float sv = x0 * shF[e][1] + x1 * shF[e][2] + x2 * shF[e][3];
    stb(svhB, e, 384, K * 2, f2bf(sv));
  }
  __syncthreads();  // BAR2: h2, svh ready

  // ---- w = h2@Wf3 + b, 3 acc ----
  {
    f32x4 acc[3] = {(f32x4){0,0,0,0}, (f32x4){0,0,0,0}, (f32x4){0,0,0,0}};
    #pragma unroll
    for (int kc = 0; kc < 2; ++kc) {
      bf16x8 a = ldb8(h2B, eA, 128, kc * 64 + cbl);
      #pragma unroll
      for (int i = 0; i < 3; ++i) {
        int up = (wn * 3 + i) * 16 + l15;
        bf16x8 b = *(const bf16x8*)(Wf3T + (size_t)up * 64 + kc * 32 + q8 * 8);
        acc[i] = __builtin_amdgcn_mfma_f32_16x16x32_bf16(a, b, acc[i], 0, 0, 0);
      }
    }
    #pragma unroll
    for (int i = 0; i < 3; ++i) {
      int up = (wn * 3 + i) * 16 + l15;
      float bias = bf3[up];
      #pragma unroll
      for (int j = 0; j < 4; ++j)
        stb(wB, mt2 * 16 + q4 + j, 384, up * 2, f2bf(acc[i][j] + bias));
    }
  }
  // ---- P3: out_s (3 acc) + t1 (1 acc) ----
  {
    f32x4 os[3] = {(f32x4){0,0,0,0}, (f32x4){0,0,0,0}, (f32x4){0,0,0,0}};
    f32x4 tt = (f32x4){0.f, 0.f, 0.f, 0.f};
    float sh0A = shF[eA][0];
    #pragma unroll
    for (int kc = 0; kc < 12; ++kc) {
      int src = kc >> 2, kk = kc & 3;
      bf16x8 a_pl, a_s0;
      if (src < 2) {
        const float* np = node_fea + (size_t)ijL[src][eA] * DIM;
        float4 r0 = *(const float4*)(np + kk * 32 + q8 * 8);
        float4 r1 = *(const float4*)(np + kk * 32 + q8 * 8 + 4);
        a_pl = pack8(r0, r1, 1.f);
        a_s0 = pack8(r0, r1, sh0A);
      } else {
        a_pl = ldb8(Ds, eA, 256, kk * 64 + cbl);
        a_s0 = scale8(a_pl, sh0A);
      }
      #pragma unroll
      for (int i = 0; i < 3; ++i) {
        int up = (wn * 3 + i) * 16 + l15;
        bf16x8 b = *(const bf16x8*)(WssT + (size_t)up * 384 + kc * 32 + q8 * 8);
        os[i] = __builtin_amdgcn_mfma_f32_16x16x32_bf16(a_s0, b, os[i], 0, 0, 0);
      }
      {
        int ut = wn * 16 + l15;
        bf16x8 b = *(const bf16x8*)(WsvT + (size_t)ut * 384 + kc * 32 + q8 * 8);
        tt = __builtin_amdgcn_mfma_f32_16x16x32_bf16(a_pl, b, tt, 0, 0, 0);
      }
    }
    #pragma unroll
    for (int kc = 0; kc < 6; ++kc) {
      bf16x8 a = ldb8(svhB, eA, 384, kc * 64 + cbl);
      #pragma unroll
      for (int i = 0; i < 3; ++i) {
        int up = (wn * 3 + i) * 16 + l15;
        bf16x8 b = *(const bf16x8*)(WvsT + (size_t)up * 192 + kc * 32 + q8 * 8);
        os[i] = __builtin_amdgcn_mfma_f32_16x16x32_bf16(a, b, os[i], 0, 0, 0);
      }
    }
    __syncthreads();  // BAR3a: wB ready (os,tt live in regs)
    #pragma unroll
    for (int i = 0; i < 3; ++i) {
      int up = (wn * 3 + i) * 16 + l15;
      #pragma unroll
      for (int j = 0; j < 4; ++j) {
        int e = mt2 * 16 + q4 + j;
        float w = bf2f(ldbs(wB, e, 384, up * 2));
        float o = os[i][j];
        if (up < 128) stb(zsB, e, 256, up * 2, f2bf(siluf_(o) * w));
        else stb(gateB, e, 128, (up - 128) * 2, f2bf(sigmoidf_(o) * w));
      }
    }
    {
      int ut = wn * 16 + l15;
      #pragma unroll
      for (int j = 0; j < 4; ++j)
        stb(t1B, mt2 * 16 + q4 + j, 128, ut * 2, f2bf(tt[j]));
    }
  }
  __syncthreads();  // BAR3b: zs, gate, t1 ready; svhB dead -> zvB reuse

  // ---- P4: out_v (3 acc), K=576 ----
  {
    f32x4 ov[3] = {(f32x4){0,0,0,0}, (f32x4){0,0,0,0}, (f32x4){0,0,0,0}};
    float sh0A = shF[eA][0];
    #pragma unroll
    for (int kc = 0; kc < 18; ++kc) {
      int src = kc / 6, kk = kc % 6;
      bf16x8 a;
      if (src < 2) {
        const float* np = node_fea + (size_t)ijL[src][eA] * DIM + 128;
        float4 r0 = *(const float4*)(np + kk * 32 + q8 * 8);
        float4 r1 = *(const float4*)(np + kk * 32 + q8 * 8 + 4);
        a = pack8(r0, r1, sh0A);
      } else {
        a = scale8(ldb8(Ev, eA, 384, kk * 64 + cbl), sh0A);
      }
      #pragma unroll
      for (int i = 0; i < 3; ++i) {
        int up = (wn * 3 + i) * 16 + l15;
        bf16x8 b = *(const bf16x8*)(WvvX + (size_t)up * 576 + kc * 32 + q8 * 8);
        ov[i] = __builtin_amdgcn_mfma_f32_16x16x32_bf16(a, b, ov[i], 0, 0, 0);
      }
    }
    #pragma unroll
    for (int i = 0; i < 3; ++i) {
      int up = (wn * 3 + i) * 16 + l15;
      int u = (up * 683) >> 11, m = up - 3 * u;
      #pragma unroll
      for (int j = 0; j < 4; ++j) {
        int e = mt2 * 16 + q4 + j;
        float t1v = bf2f(ldbs(t1B, e, 128, u * 2));
        float g = bf2f(ldbs(gateB, e, 128, u * 2));
        float val = ov[i][j] + t1v * shF[e][1 + m];
        stb(zvB, e, 384, up * 2, f2bf(val * g));
      }
    }
  }
  __syncthreads();  // BAR4: zs, zv ready

  // ---- P5: post linears, RMW accumulate onto sc in d_out ----
  {
    f32x4 p0[2] = {(f32x4){0,0,0,0}, (f32x4){0,0,0,0}};
    #pragma unroll
    for (int kc = 0; kc < 4; ++kc) {
      bf16x8 a = ldb8(zsB, eA, 256, kc * 64 + cbl);
      #pragma unroll
      for (int i = 0; i < 2; ++i) {
        int u = (wn * 2 + i) * 16 + l15;
        bf16x8 b = *(const bf16x8*)(Wpost0T + (size_t)u * 128 + kc * 32 + q8 * 8);
        p0[i] = __builtin_amdgcn_mfma_f32_16x16x32_bf16(a, b, p0[i], 0, 0, 0);
      }
    }
    #pragma unroll
    for (int i = 0; i < 2; ++i) {
      int u = (wn * 2 + i) * 16 + l15;
      float bias = bpost0[u];
      #pragma unroll
      for (int j = 0; j < 4; ++j) {
        size_t o = (size_t)(e0 + mt2 * 16 + q4 + j) * DIM + u;
        out[o] = out[o] + p0[i][j] + bias;
      }
    }
    f32x4 p1a[3] = {(f32x4){0,0,0,0}, (f32x4){0,0,0,0}, (f32x4){0,0,0,0}};
    #pragma unroll
    for (int kc = 0; kc < 6; ++kc) {
      bf16x8 a = ldb8(zvB, eA, 384, kc * 64 + cbl);
      #pragma unroll
      for (int i = 0; i < 3; ++i) {
        int up = (wn * 3 + i) * 16 + l15;
        bf16x8 b = *(const bf16x8*)(Wpost1X + (size_t)up * 192 + kc * 32 + q8 * 8);
        p1a[i] = __builtin_amdgcn_mfma_f32_16x16x32_bf16(a, b, p1a[i], 0, 0, 0);
      }
    }
    #pragma unroll
    for (int i = 0; i < 3; ++i) {
      int up = (wn * 3 + i) * 16 + l15;
      #pragma unroll
      for (int j = 0; j < 4; ++j) {
        size_t o = (size_t)(e0 + mt2 * 16 + q4 + j) * DIM + 128 + up;
        out[o] = out[o] + p1a[i][j];
      }
    }
  }
}

// ---------------- K3: group statistics ----------------
__global__ __launch_bounds__(256) void k_stats(
    const float* __restrict__ out, const int* __restrict__ eidx,
    const int* __restrict__ batch, float* __restrict__ stats) {
  __shared__ float gacc[16][4];
  const int t = threadIdx.x;
  if (t < 64) ((float*)gacc)[t] = 0.0f;
  __syncthreads();
  const int el = t >> 4, l = t & 15;
  for (int ebase = blockIdx.x * 16; ebase < E_TOT; ebase += gridDim.x * 16) {
    int e = ebase + el;
    const float* z = out + (size_t)e * DIM;
    float s1 = 0, s2 = 0, s2v = 0;
    for (int c = l; c < 128; c += 16) { float x = z[c]; s1 += x; s2 += x * x; }
    for (int c = 128 + l; c < DIM; c += 16) { float x = z[c]; s2v += x * x; }
    #pragma unroll
    for (int msk = 8; msk; msk >>= 1) {
      s1 += __shfl_xor(s1, msk);
      s2 += __shfl_xor(s2, msk);
      s2v += __shfl_xor(s2v, msk);
    }
    if (l == 0) {
      int g = batch[eidx[e]];
      atomicAdd(&gacc[g][0], 1.0f);
      atomicAdd(&gacc[g][1], s1);
      atomicAdd(&gacc[g][2], s2);
      atomicAdd(&gacc[g][3], s2v);
    }
  }
  __syncthreads();
  if (t < 64) {
    float v = gacc[t >> 2][t & 3];
    if (v != 0.0f) atomicAdd(&stats[(t >> 2) * 16 + (t & 3)], v);
  }
}

// ---------------- K4: normalize + residual ----------------
__global__ __launch_bounds__(256) void k_norm(
    const float* __restrict__ edge_fea, const int* __restrict__ eidx,
    const int* __restrict__ batch, const float* __restrict__ stats,
    const float* __restrict__ gamma_s, const float* __restrict__ beta_s,
    const float* __restrict__ gamma_v, float* __restrict__ out) {
  __shared__ float meanL[16], invsL[16], invvL[16];
  __shared__ int gL[ET];
  const int t = threadIdx.x;
  const int e0 = blockIdx.x * ET;
  if (t < 16) {
    float cnt = fmaxf(stats[t * 16 + 0], 1.0f);
    float m = stats[t * 16 + 1] / (cnt * 128.0f);
    float var = stats[t * 16 + 2] / (cnt * 128.0f) - m * m;
    meanL[t] = m;
    invsL[t] = rsqrtf(var + 1e-5f);
    invvL[t] = rsqrtf(stats[t * 16 + 3] / (cnt * 192.0f) + 1e-5f);
  }
  if (t >= 32 && t < 32 + ET) gL[t - 32] = batch[eidx[e0 + t - 32]];
  __syncthreads();
  for (int o = t; o < ET * DIM; o += 256) {
    int e = o / DIM, c = o % DIM;
    int g = gL[e];
    size_t idx = (size_t)(e0 + e) * DIM + c;
    float z = out[idx];
    float r;
    if (c < 128) r = (z - meanL[g]) * invsL[g] * gamma_s[c] + beta_s[c];
    else r = z * invvL[g] * gamma_v[(c - 128) / 3];
    out[idx] = r + edge_fea[idx];
  }
}

extern "C" void kernel_launch(void* const* d_in, const int* in_sizes, int n_in,
                              void* d_out, int out_size, void* d_ws, size_t ws_size,
                              hipStream_t stream) {
  const float* node_fea = (const float*)d_in[0];
  const float* edge_oh  = (const float*)d_in[1];
  const float* edge_sh  = (const float*)d_in[2];
  const float* edge_fea = (const float*)d_in[3];
  const float* elen     = (const float*)d_in[4];
  const int*   eidx     = (const int*)d_in[5];
  const int*   batch    = (const int*)d_in[6];
  const float* Wsc_s    = (const float*)d_in[7];
  const float* Wsc_v    = (const float*)d_in[8];
  const float* Wpre0    = (const float*)d_in[9];
  const float* bpre0    = (const float*)d_in[10];
  const float* Wpre1    = (const float*)d_in[11];
  const float* Wss      = (const float*)d_in[12];
  const float* Wvs      = (const float*)d_in[13];
  const float* Wsv      = (const float*)d_in[14];
  const float* Wvv      = (const float*)d_in[15];
  const float* Wf1      = (const float*)d_in[16];
  const float* bf1      = (const float*)d_in[17];
  const float* Wf2      = (const float*)d_in[18];
  const float* bf2      = (const float*)d_in[19];
  const float* Wf3      = (const float*)d_in[20];
  const float* bf3      = (const float*)d_in[21];
  const float* Wpost0   = (const float*)d_in[22];
  const float* bpost0   = (const float*)d_in[23];
  const float* Wpost1   = (const float*)d_in[24];
  const float* gamma_s  = (const float*)d_in[25];
  const float* beta_s   = (const float*)d_in[26];
  const float* gamma_v  = (const float*)d_in[27];
  float* out = (float*)d_out;

  char* ws = (char*)d_ws;
  float* stats = (float*)ws;
  u16* wbf = (u16*)(ws + 1024);

  hipMemsetAsync(stats, 0, 16 * 16 * sizeof(float), stream);
  k_prep<<<(OW_END + 255) / 256, 256, 0, stream>>>(
      Wsc_s, Wsc_v, Wpre0, Wpre1, Wss, Wvs, Wsv, Wvv,
      Wf1, Wf2, Wf3, Wpost0, Wpost1, wbf);
  const int nblk64 = (E_TOT + 63) / 64;  // 1563
  k_sc_s<<<nblk64, 256, 0, stream>>>(edge_fea, edge_oh, wbf + OW_W2S, out);
  k_sc_v<<<nblk64, 256, 0, stream>>>(edge_fea, edge_oh, wbf + OW_SCV, out);
  k_chain<<<E_TOT / 32, 512, 0, stream>>>(node_fea, edge_sh, edge_fea, elen, eidx,
                                          wbf, bpre0, bf1, bf2, bf3, bpost0, out);
  k_stats<<<512, 256, 0, stream>>>(out, eidx, batch, stats);
  k_norm<<<E_TOT / ET, 256, 0, stream>>>(edge_fea, eidx, batch, stats,
                                         gamma_s, beta_s, gamma_v, out);
}

// Round 5
// 1075.093 us; speedup vs baseline: 2.2976x; 2.2976x over previous
//
#include <hip/hip_runtime.h>
#include <math.h>

typedef unsigned int u32;
typedef unsigned short u16;
typedef __attribute__((ext_vector_type(8))) short bf16x8;
typedef __attribute__((ext_vector_type(4))) float f32x4;

#define E_TOT 100000
#define ET 16
constexpr int NS = 128, NV = 64, DIM = 320;

constexpr float SC_S_SCALE = 0.022097086912079608f;  // 1/sqrt(128*16)
constexpr float SC_V_SCALE = 0.03125f;               // 1/32
constexpr float INV_SQRT128 = 0.08838834764831845f;
constexpr float INV_8 = 0.125f;
constexpr float INV_S384 = 0.05103103630798288f;     // 1/sqrt(384)
constexpr float INV_24 = 0.041666666666666664f;      // 1/sqrt(576)
constexpr float INV_S192 = 0.07216878364870323f;     // 1/sqrt(192)
constexpr float RSQRT2 = 0.7071067811865476f;

__device__ __forceinline__ float sigmoidf_(float x) { return 1.0f / (1.0f + __expf(-x)); }
__device__ __forceinline__ float siluf_(float x) { return x * sigmoidf_(x); }

__device__ __forceinline__ float bf2f(u16 h) {
  u32 u = ((u32)h) << 16;
  return __builtin_bit_cast(float, u);
}
__device__ __forceinline__ u16 f2bf(float f) {
  u32 u = __builtin_bit_cast(u32, f);
  return (u16)((u + 0x7fffu + ((u >> 16) & 1u)) >> 16);
}
__device__ __forceinline__ void gl_lds16(const void* g, void* l) {
  __builtin_amdgcn_global_load_lds((const __attribute__((address_space(1))) u32*)g,
                                   (__attribute__((address_space(3))) u32*)l, 16, 0, 0);
}
// swizzled bf16 LDS store/load (XOR byte bits 4-6 with row&7) — rowB multiple of 128
__device__ __forceinline__ void stb(char* base, int row, int rowB, int colByte, u16 v) {
  *(u16*)(base + row * rowB + (colByte ^ ((row & 7) << 4))) = v;
}
__device__ __forceinline__ u16 ldbs(const char* base, int row, int rowB, int colByte) {
  return *(const u16*)(base + row * rowB + (colByte ^ ((row & 7) << 4)));
}
__device__ __forceinline__ bf16x8 ldb8(const char* base, int row, int rowB, int colByte) {
  return *(const bf16x8*)(base + row * rowB + (colByte ^ ((row & 7) << 4)));
}

// ---------------- workspace layout ----------------
// bytes: 0 stats (1KB); 1024 bf16 weights (1081344B); then outs/outv bf16 [E][192]
#define OFF_WBF   1024
#define OFF_OUTS  1082368
#define OFF_OUTV  39482368
#define WS_NEED   77882368
// element offsets in bf16 weight arena. sc parts keep R2 layout (for LDS staging);
// chain parts are FRAGMENT-LINEAR: elem = (ntile*(K/32)+kc)*512 + lane*8 + j
// holding W^T[ntile*16+(lane&15)][kc*32+(lane>>4)*8+j] (scales folded).
#define C0      262144   /* W2s  (Wsc_s^T [128][2048]) */
#define C1      327680   /* Btv  (Wsc_v^T [64][1024]) */
#define FR_PRE0 327680   /* N=128 K=128 */
#define FR_PRE1 344064   /* N=64  K=64  */
#define FR_SS   348160   /* N=192 K=384 */
#define FR_VS   421888   /* N=192 K=192 */
#define FR_SV   458752   /* N=64  K=384 */
#define FR_VV   483328   /* N=64  K=192 */
#define FR_F1   495616   /* N=64  K=128 */
#define FR_F2   503808   /* N=64  K=64  */
#define FR_F3   507904   /* N=192 K=64  */
#define FR_P0   520192   /* N=128 K=128 */
#define FR_P1   536576   /* N=64  K=64  */
#define FR_END  540672

// ---------------- K0: weight prep ----------------
__device__ __forceinline__ float frag_src(int oo, int N, int K, const float* W, float scale) {
  int per = (K >> 5) << 9;           // (K/32)*512
  int nt = oo / per, r = oo % per;
  int kc = r >> 9, r2 = r & 511;
  int lane = r2 >> 3, j = r2 & 7;
  int u = nt * 16 + (lane & 15);
  int k = kc * 32 + (lane >> 4) * 8 + j;
  return W[(size_t)k * N + u] * scale;
}

__global__ __launch_bounds__(256) void k_prep(
    const float* __restrict__ Wsc_s, const float* __restrict__ Wsc_v,
    const float* __restrict__ Wpre0, const float* __restrict__ Wpre1,
    const float* __restrict__ Wss, const float* __restrict__ Wvs,
    const float* __restrict__ Wsv, const float* __restrict__ Wvv,
    const float* __restrict__ Wf1, const float* __restrict__ Wf2,
    const float* __restrict__ Wf3, const float* __restrict__ Wpost0,
    const float* __restrict__ Wpost1, u16* __restrict__ dst) {
  int o = blockIdx.x * 256 + threadIdx.x;
  if (o >= FR_END) return;
  float v;
  if (o < C0) { int u = o >> 11, k = o & 2047, s = k >> 7, vv = k & 127;
    v = Wsc_s[((size_t)(vv * 16 + s)) * 128 + u]; }
  else if (o < C1) { int oo = o - C0; int u = oo >> 10, k = oo & 1023, s = k >> 6, vv = k & 63;
    v = Wsc_v[((size_t)(vv * 16 + s)) * 64 + u]; }
  else if (o < FR_PRE1) v = frag_src(o - FR_PRE0, 128, 128, Wpre0, INV_SQRT128);
  else if (o < FR_SS)   v = frag_src(o - FR_PRE1, 64, 64, Wpre1, INV_8);
  else if (o < FR_VS)   v = frag_src(o - FR_SS, 192, 384, Wss, INV_S384 * RSQRT2);
  else if (o < FR_SV)   v = frag_src(o - FR_VS, 192, 192, Wvs, INV_24 * RSQRT2);
  else if (o < FR_VV)   v = frag_src(o - FR_SV, 64, 384, Wsv, INV_S384 * RSQRT2);
  else if (o < FR_F1)   v = frag_src(o - FR_VV, 64, 192, Wvv, INV_S192 * RSQRT2);
  else if (o < FR_F2)   v = frag_src(o - FR_F1, 64, 128, Wf1, 1.0f);
  else if (o < FR_F3)   v = frag_src(o - FR_F2, 64, 64, Wf2, 1.0f);
  else if (o < FR_P0)   v = frag_src(o - FR_F3, 192, 64, Wf3, 1.0f);
  else if (o < FR_P1)   v = frag_src(o - FR_P0, 128, 128, Wpost0, INV_SQRT128);
  else                  v = frag_src(o - FR_P1, 64, 64, Wpost1, INV_8);
  dst[o] = f2bf(v);
}

// ---------------- K1a: sc_s via MFMA (verified R2) ----------------
#define MEs 64
__global__ __launch_bounds__(256, 2) void k_sc_s(
    const float* __restrict__ edge_fea, const float* __restrict__ ohp,
    const u16* __restrict__ W2s, float* __restrict__ out) {
  __shared__ u16 esB[64][136];
  __shared__ float ohL[64][16];
  __shared__ u16 Abuf[64 * 128];
  __shared__ u16 Bbuf[128 * 128];
  const int t = threadIdx.x;
  const int lane = t & 63, ww = t >> 6;
  const int e0 = blockIdx.x * MEs;
  const int nE = min(MEs, E_TOT - e0);

  for (int o = t; o < 64 * 32; o += 256) {
    int e = o >> 5, c4 = (o & 31) << 2;
    float4 x = (e < nE) ? *(const float4*)&edge_fea[(size_t)(e0 + e) * DIM + c4]
                        : make_float4(0.f, 0.f, 0.f, 0.f);
    esB[e][c4 + 0] = f2bf(x.x); esB[e][c4 + 1] = f2bf(x.y);
    esB[e][c4 + 2] = f2bf(x.z); esB[e][c4 + 3] = f2bf(x.w);
  }
  for (int o = t; o < 64 * 16; o += 256) {
    int e = o >> 4, s = o & 15;
    ohL[e][s] = (e < nE) ? ohp[(size_t)(e0 + e) * 16 + s] : 0.f;
  }
  __syncthreads();

  f32x4 acc[4][2];
  #pragma unroll
  for (int a = 0; a < 4; ++a)
    #pragma unroll
    for (int b = 0; b < 2; ++b) acc[a][b] = (f32x4){0.f, 0.f, 0.f, 0.f};

  for (int s = 0; s < 16; ++s) {
    {
      const char* sb = (const char*)W2s + s * 256;
      #pragma unroll
      for (int it = 0; it < 8; ++it) {
        int n = it * 256 + t;
        int u = n >> 4, gp = n & 15, g = gp ^ (u & 7);
        gl_lds16(sb + (size_t)u * 4096 + g * 16, (char*)Bbuf + n * 16);
      }
    }
    #pragma unroll
    for (int it = 0; it < 4; ++it) {
      int n = it * 256 + t;
      int e = n >> 4, gp = n & 15, g = gp ^ (e & 7);
      float ohs = ohL[e][s];
      union { uint4 q; u16 h[8]; } in, ov;
      in.q = *(const uint4*)&esB[e][g * 8];
      #pragma unroll
      for (int j = 0; j < 8; ++j) ov.h[j] = f2bf(bf2f(in.h[j]) * ohs);
      *(uint4*)((char*)Abuf + e * 256 + gp * 16) = ov.q;
    }
    __syncthreads();

    const int cbl = (lane >> 4) << 4;
    #pragma unroll
    for (int ks = 0; ks < 4; ++ks) {
      int cbyte = ks * 64 + cbl;
      bf16x8 bfr[2], afr[4];
      #pragma unroll
      for (int ct = 0; ct < 2; ++ct) {
        int u = ww * 32 + ct * 16 + (lane & 15);
        bfr[ct] = *(const bf16x8*)((const char*)Bbuf + u * 256 + (cbyte ^ ((u & 7) << 4)));
      }
      #pragma unroll
      for (int rt = 0; rt < 4; ++rt) {
        int e = rt * 16 + (lane & 15);
        afr[rt] = *(const bf16x8*)((const char*)Abuf + e * 256 + (cbyte ^ ((e & 7) << 4)));
      }
      #pragma unroll
      for (int rt = 0; rt < 4; ++rt)
        #pragma unroll
        for (int ct = 0; ct < 2; ++ct)
          acc[rt][ct] = __builtin_amdgcn_mfma_f32_16x16x32_bf16(afr[rt], bfr[ct], acc[rt][ct], 0, 0, 0);
    }
    __syncthreads();
  }

  #pragma unroll
  for (int rt = 0; rt < 4; ++rt) {
    int ebase = rt * 16 + ((lane >> 4) << 2);
    #pragma unroll
    for (int ct = 0; ct < 2; ++ct) {
      int u = ww * 32 + ct * 16 + (lane & 15);
      #pragma unroll
      for (int j = 0; j < 4; ++j) {
        int ee = ebase + j;
        if (ee < nE) out[(size_t)(e0 + ee) * DIM + u] = acc[rt][ct][j] * SC_S_SCALE;
      }
    }
  }
}

// ---------------- K1b: sc_v via MFMA (verified R2) ----------------
__global__ __launch_bounds__(256, 2) void k_sc_v(
    const float* __restrict__ edge_fea, const float* __restrict__ ohp,
    const u16* __restrict__ Btv, float* __restrict__ out) {
  __shared__ u16 evT[3][64][72];
  __shared__ float ohL[64][16];
  __shared__ u16 Abuf[192 * 64];
  __shared__ u16 Bbuf[64 * 64];
  const int t = threadIdx.x;
  const int lane = t & 63, ww = t >> 6;
  const int e0 = blockIdx.x * MEs;
  const int nE = min(MEs, E_TOT - e0);

  for (int o = t; o < 64 * 192; o += 256) {
    int e = o / 192, c = o % 192;
    int v = c / 3, m = c % 3;
    float x = (e < nE) ? edge_fea[(size_t)(e0 + e) * DIM + NS + c] : 0.f;
    evT[m][e][v] = f2bf(x);
  }
  for (int o = t; o < 64 * 16; o += 256) {
    int e = o >> 4, s = o & 15;
    ohL[e][s] = (e < nE) ? ohp[(size_t)(e0 + e) * 16 + s] : 0.f;
  }
  __syncthreads();

  f32x4 acc[12];
  #pragma unroll
  for (int a = 0; a < 12; ++a) acc[a] = (f32x4){0.f, 0.f, 0.f, 0.f};

  for (int s = 0; s < 16; ++s) {
    #pragma unroll
    for (int it = 0; it < 2; ++it) {
      int n = it * 256 + t;
      int u = n >> 3, gp = n & 7, g = gp ^ (u & 7);
      gl_lds16((const char*)Btv + (size_t)u * 2048 + s * 128 + g * 16, (char*)Bbuf + n * 16);
    }
    #pragma unroll
    for (int it = 0; it < 6; ++it) {
      int n = it * 256 + t;
      int r = n >> 3, gp = n & 7, g = gp ^ (r & 7);
      int e = r / 3, m = r - e * 3;
      float ohs = ohL[e][s];
      union { uint4 q; u16 h[8]; } in, ov;
      in.q = *(const uint4*)&evT[m][e][g * 8];
      #pragma unroll
      for (int j = 0; j < 8; ++j) ov.h[j] = f2bf(bf2f(in.h[j]) * ohs);
      *(uint4*)((char*)Abuf + r * 128 + gp * 16) = ov.q;
    }
    __syncthreads();

    const int cbl = (lane >> 4) << 4;
    #pragma unroll
    for (int ks = 0; ks < 2; ++ks) {
      int cbyte = ks * 64 + cbl;
      int u = ww * 16 + (lane & 15);
      bf16x8 bfr = *(const bf16x8*)((const char*)Bbuf + u * 128 + (cbyte ^ ((u & 7) << 4)));
      #pragma unroll
      for (int rt = 0; rt < 12; ++rt) {
        int r = rt * 16 + (lane & 15);
        bf16x8 afr = *(const bf16x8*)((const char*)Abuf + r * 128 + (cbyte ^ ((r & 7) << 4)));
        acc[rt] = __builtin_amdgcn_mfma_f32_16x16x32_bf16(afr, bfr, acc[rt], 0, 0, 0);
      }
    }
    __syncthreads();
  }

  #pragma unroll
  for (int rt = 0; rt < 12; ++rt) {
    int rbase = rt * 16 + ((lane >> 4) << 2);
    int u = ww * 16 + (lane & 15);
    #pragma unroll
    for (int j = 0; j < 4; ++j) {
      int r = rbase + j;
      int e = r / 3, m = r - e * 3;
      if (e < nE) out[(size_t)(e0 + e) * DIM + NS + u * 3 + m] = acc[rt][j] * SC_V_SCALE;
    }
  }
}

// ---------------- K2a: pre-linears + mixing (MFMA), fragment-linear B ----------------
__global__ __launch_bounds__(512, 1) void k2a(
    const float* __restrict__ node_fea, const float* __restrict__ edge_sh,
    const float* __restrict__ edge_fea, const int* __restrict__ eidx,
    const u16* __restrict__ wbf, const float* __restrict__ bpre0,
    u16* __restrict__ outsG, u16* __restrict__ outvG) {
  __shared__ char AR[155648];
  __shared__ float shF[64][4];
  __shared__ int iL[64], jL[64];
  const int t = threadIdx.x, lane = t & 63, wv = t >> 6;
  const int l15 = lane & 15, q4 = (lane >> 4) << 2, cbl = (lane >> 4) << 4;
  const int e0 = blockIdx.x * 64;
  const int nE = min(64, E_TOT - e0);
  char* sin2 = AR + 32768;
  char* vin2 = AR + 98304;
  char* svh  = AR + 122880;
  char* t1B  = AR + 147456;

  if (t < 64) { iL[t] = (t < nE) ? eidx[e0 + t] : 0; jL[t] = (t < nE) ? eidx[E_TOT + e0 + t] : 0; }
  for (int o = t; o < 256; o += 512) {
    int e = o >> 2, m = o & 3;
    shF[e][m] = (e < nE) ? edge_sh[(size_t)(e0 + e) * 4 + m] : 0.f;
  }
  __syncthreads();

  for (int o = t; o < 64 * 80; o += 512) {
    int e = o / 80, q = o % 80;
    float4 x = (e < nE) ? ((const float4*)edge_fea)[(size_t)(e0 + e) * 80 + q]
                        : make_float4(0.f, 0.f, 0.f, 0.f);
    int c = q * 4;
    #pragma unroll
    for (int z = 0; z < 4; ++z) {
      float val = (&x.x)[z]; int cc = c + z;
      if (cc < 128) stb(sin2, e, 256, cc * 2, f2bf(val));
      else { int v = (cc - 128) / 3, m = (cc - 128) % 3; stb(vin2, m * 64 + e, 128, v * 2, f2bf(val)); }
    }
  }
  for (int o = t; o < 2 * 64 * 80; o += 512) {
    int p = o / 80, q = o % 80;
    int e = p >> 1, wh = p & 1;
    int n = wh ? jL[e] : iL[e];
    float4 x = (e < nE) ? ((const float4*)node_fea)[(size_t)n * 80 + q]
                        : make_float4(0.f, 0.f, 0.f, 0.f);
    char* sB = AR + wh * 16384;
    char* vB = AR + 49152 + wh * 24576;
    int c = q * 4;
    #pragma unroll
    for (int z = 0; z < 4; ++z) {
      float val = (&x.x)[z]; int cc = c + z;
      if (cc < 128) stb(sB, e, 256, cc * 2, f2bf(val));
      else { int v = (cc - 128) / 3, m = (cc - 128) % 3; stb(vB, m * 64 + e, 128, v * 2, f2bf(val)); }
    }
  }
  __syncthreads();

  // ---- P1: s = es@Wpre0'+b (waves 0-3), v = ev@Wpre1' (waves 4-7)
  f32x4 p1[12];
  #pragma unroll
  for (int a = 0; a < 12; ++a) p1[a] = (f32x4){0.f, 0.f, 0.f, 0.f};
  if (wv < 4) {
    for (int kc = 0; kc < 4; ++kc) {
      int cbyte = kc * 64 + cbl;
      bf16x8 b0 = *(const bf16x8*)(wbf + FR_PRE0 + ((size_t)(wv * 2 + 0) * 4 + kc) * 512 + lane * 8);
      bf16x8 b1 = *(const bf16x8*)(wbf + FR_PRE0 + ((size_t)(wv * 2 + 1) * 4 + kc) * 512 + lane * 8);
      #pragma unroll
      for (int mt = 0; mt < 4; ++mt) {
        bf16x8 a = ldb8(sin2, mt * 16 + l15, 256, cbyte);
        p1[mt * 2 + 0] = __builtin_amdgcn_mfma_f32_16x16x32_bf16(a, b0, p1[mt * 2 + 0], 0, 0, 0);
        p1[mt * 2 + 1] = __builtin_amdgcn_mfma_f32_16x16x32_bf16(a, b1, p1[mt * 2 + 1], 0, 0, 0);
      }
    }
  } else {
    for (int kc = 0; kc < 2; ++kc) {
      int cbyte = kc * 64 + cbl;
      bf16x8 b = *(const bf16x8*)(wbf + FR_PRE1 + ((size_t)(wv - 4) * 2 + kc) * 512 + lane * 8);
      #pragma unroll
      for (int mt = 0; mt < 12; ++mt) {
        bf16x8 a = ldb8(vin2, mt * 16 + l15, 128, cbyte);
        p1[mt] = __builtin_amdgcn_mfma_f32_16x16x32_bf16(a, b, p1[mt], 0, 0, 0);
      }
    }
  }
  __syncthreads();
  if (wv < 4) {
    #pragma unroll
    for (int mt = 0; mt < 4; ++mt)
      #pragma unroll
      for (int nt = 0; nt < 2; ++nt) {
        int u = wv * 32 + nt * 16 + l15;
        float bias = bpre0[u];
        #pragma unroll
        for (int j = 0; j < 4; ++j) {
          int e = mt * 16 + q4 + j;
          stb(sin2, e, 256, u * 2, f2bf(p1[mt * 2 + nt][j] + bias));
        }
      }
  } else {
    #pragma unroll
    for (int mt = 0; mt < 12; ++mt) {
      int u = (wv - 4) * 16 + l15;
      #pragma unroll
      for (int j = 0; j < 4; ++j) {
        int r = mt * 16 + q4 + j;
        stb(vin2, r, 128, u * 2, f2bf(p1[mt][j]));
      }
    }
  }
  __syncthreads();

  // ---- P2: svh[e][k]
  for (int o = t; o < 64 * 192; o += 512) {
    int e = o / 192, k = o % 192;
    int buf = k >> 6, kk = k & 63;
    const char* vb = AR + 49152 + buf * 24576;
    float s = 0.f;
    #pragma unroll
    for (int m = 0; m < 3; ++m) {
      u16 hv = *(const u16*)(vb + (m * 64 + e) * 128 + ((kk * 2) ^ ((e & 7) << 4)));
      s += bf2f(hv) * shF[e][m + 1];
    }
    stb(svh, e, 384, k * 2, f2bf(s));
  }

  // ---- P3a: t1 = s_in@Wsv' (16 tiles, 2/wave)
  {
    f32x4 at[2];
    at[0] = (f32x4){0.f, 0.f, 0.f, 0.f}; at[1] = at[0];
    int tmt[2], tnt[2];
    #pragma unroll
    for (int i = 0; i < 2; ++i) { int tile = wv * 2 + i; tmt[i] = tile >> 2; tnt[i] = tile & 3; }
    for (int kc = 0; kc < 12; ++kc) {
      int cbyte = (kc & 3) * 64 + cbl;
      const char* ab = AR + (kc >> 2) * 16384;
      #pragma unroll
      for (int i = 0; i < 2; ++i) {
        bf16x8 a = ldb8(ab, tmt[i] * 16 + l15, 256, cbyte);
        bf16x8 b = *(const bf16x8*)(wbf + FR_SV + ((size_t)tnt[i] * 12 + kc) * 512 + lane * 8);
        at[i] = __builtin_amdgcn_mfma_f32_16x16x32_bf16(a, b, at[i], 0, 0, 0);
      }
    }
    #pragma unroll
    for (int i = 0; i < 2; ++i) {
      int u = tnt[i] * 16 + l15;
      #pragma unroll
      for (int j = 0; j < 4; ++j) {
        int e = tmt[i] * 16 + q4 + j;
        stb(t1B, e, 128, u * 2, f2bf(at[i][j]));
      }
    }
  }
  __syncthreads();

  // ---- P3b: out_s then out_v
  {
    f32x4 as_[6];
    #pragma unroll
    for (int a = 0; a < 6; ++a) as_[a] = (f32x4){0.f, 0.f, 0.f, 0.f};
    const int smt = wv >> 1, snb = (wv & 1) * 6;
    for (int kc = 0; kc < 12; ++kc) {
      int cbyte = (kc & 3) * 64 + cbl;
      bf16x8 a = ldb8(AR + (kc >> 2) * 16384, smt * 16 + l15, 256, cbyte);
      #pragma unroll
      for (int nt = 0; nt < 6; ++nt) {
        bf16x8 b = *(const bf16x8*)(wbf + FR_SS + ((size_t)(snb + nt) * 12 + kc) * 512 + lane * 8);
        as_[nt] = __builtin_amdgcn_mfma_f32_16x16x32_bf16(a, b, as_[nt], 0, 0, 0);
      }
    }
    #pragma unroll
    for (int nt = 0; nt < 6; ++nt)
      #pragma unroll
      for (int j = 0; j < 4; ++j) as_[nt][j] *= shF[smt * 16 + q4 + j][0];
    for (int kc = 0; kc < 6; ++kc) {
      int cbyte = kc * 64 + cbl;
      bf16x8 a = ldb8(svh, smt * 16 + l15, 384, cbyte);
      #pragma unroll
      for (int nt = 0; nt < 6; ++nt) {
        bf16x8 b = *(const bf16x8*)(wbf + FR_VS + ((size_t)(snb + nt) * 6 + kc) * 512 + lane * 8);
        as_[nt] = __builtin_amdgcn_mfma_f32_16x16x32_bf16(a, b, as_[nt], 0, 0, 0);
      }
    }
    #pragma unroll
    for (int nt = 0; nt < 6; ++nt) {
      int u = (snb + nt) * 16 + l15;
      #pragma unroll
      for (int j = 0; j < 4; ++j) {
        int e = smt * 16 + q4 + j;
        if (e < nE) outsG[(size_t)(e0 + e) * 192 + u] = f2bf(as_[nt][j]);
      }
    }

    f32x4 av[6];
    #pragma unroll
    for (int a = 0; a < 6; ++a) av[a] = (f32x4){0.f, 0.f, 0.f, 0.f};
    for (int kc = 0; kc < 6; ++kc) {
      int cbyte = (kc & 1) * 64 + cbl;
      const char* vb = AR + 49152 + (kc >> 1) * 24576;
      #pragma unroll
      for (int i = 0; i < 6; ++i) {
        int tile = wv * 6 + i, mt = tile >> 2, nt = tile & 3;
        bf16x8 a = ldb8(vb, mt * 16 + l15, 128, cbyte);
        bf16x8 b = *(const bf16x8*)(wbf + FR_VV + ((size_t)nt * 6 + kc) * 512 + lane * 8);
        av[i] = __builtin_amdgcn_mfma_f32_16x16x32_bf16(a, b, av[i], 0, 0, 0);
      }
    }
    #pragma unroll
    for (int i = 0; i < 6; ++i) {
      int tile = wv * 6 + i, mt = tile >> 2, nt = tile & 3;
      int u = nt * 16 + l15;
      #pragma unroll
      for (int j = 0; j < 4; ++j) {
        int r = mt * 16 + q4 + j;
        int m = r >> 6, e = r & 63;
        float t1v = bf2f(*(const u16*)(t1B + e * 128 + ((u * 2) ^ ((e & 7) << 4))));
        float val = av[i][j] * shF[e][0] + t1v * shF[e][1 + m];
        if (e < nE) outvG[(size_t)(e0 + e) * 192 + m * 64 + u] = f2bf(val);
      }
    }
  }
}

// ---------------- K2b: MLP + gating + post linears (fragment-linear B) ----------
__global__ __launch_bounds__(256, 2) void k2b(
    const float* __restrict__ elen, const u16* __restrict__ wbf,
    const float* __restrict__ bf1, const float* __restrict__ bf2,
    const float* __restrict__ bf3, const float* __restrict__ bpost0,
    const u16* __restrict__ outsG, const u16* __restrict__ outvG,
    float* __restrict__ out) {
  __shared__ char AR[65536];
  const int t = threadIdx.x, lane = t & 63, wv = t >> 6;
  const int l15 = lane & 15, q4 = (lane >> 4) << 2, cbl = (lane >> 4) << 4;
  const int e0 = blockIdx.x * 64;
  const int nE = min(64, E_TOT - e0);
  char* elB = AR;
  char* h1B = AR;
  char* h2B = AR + 8192;
  char* wB  = AR + 16384;
  char* zsA = AR;
  char* zvA = AR + 40960;

  for (int o = t; o < 64 * 32; o += 256) {
    int e = o >> 5, q = o & 31;
    float4 x = (e < nE) ? ((const float4*)elen)[(size_t)(e0 + e) * 32 + q]
                        : make_float4(0.f, 0.f, 0.f, 0.f);
    int c = q * 4;
    stb(elB, e, 256, (c + 0) * 2, f2bf(x.x)); stb(elB, e, 256, (c + 1) * 2, f2bf(x.y));
    stb(elB, e, 256, (c + 2) * 2, f2bf(x.z)); stb(elB, e, 256, (c + 3) * 2, f2bf(x.w));
  }
  __syncthreads();

  // h1
  {
    f32x4 acc[4];
    #pragma unroll
    for (int a = 0; a < 4; ++a) acc[a] = (f32x4){0.f, 0.f, 0.f, 0.f};
    for (int kc = 0; kc < 4; ++kc) {
      int cbyte = kc * 64 + cbl;
      bf16x8 b = *(const bf16x8*)(wbf + FR_F1 + ((size_t)wv * 4 + kc) * 512 + lane * 8);
      #pragma unroll
      for (int mt = 0; mt < 4; ++mt) {
        bf16x8 a = ldb8(elB, mt * 16 + l15, 256, cbyte);
        acc[mt] = __builtin_amdgcn_mfma_f32_16x16x32_bf16(a, b, acc[mt], 0, 0, 0);
      }
    }
    __syncthreads();
    int u = wv * 16 + l15;
    float bias = bf1[u];
    #pragma unroll
    for (int mt = 0; mt < 4; ++mt)
      #pragma unroll
      for (int j = 0; j < 4; ++j)
        stb(h1B, mt * 16 + q4 + j, 128, u * 2, f2bf(siluf_(acc[mt][j] + bias)));
  }
  __syncthreads();
  // h2
  {
    f32x4 acc[4];
    #pragma unroll
    for (int a = 0; a < 4; ++a) acc[a] = (f32x4){0.f, 0.f, 0.f, 0.f};
    for (int kc = 0; kc < 2; ++kc) {
      int cbyte = kc * 64 + cbl;
      bf16x8 b = *(const bf16x8*)(wbf + FR_F2 + ((size_t)wv * 2 + kc) * 512 + lane * 8);
      #pragma unroll
      for (int mt = 0; mt < 4; ++mt) {
        bf16x8 a = ldb8(h1B, mt * 16 + l15, 128, cbyte);
        acc[mt] = __builtin_amdgcn_mfma_f32_16x16x32_bf16(a, b, acc[mt], 0, 0, 0);
      }
    }
    __syncthreads();
    int u = wv * 16 + l15;
    float bias = bf2[u];
    #pragma unroll
    for (int mt = 0; mt < 4; ++mt)
      #pragma unroll
      for (int j = 0; j < 4; ++j)
        stb(h2B, mt * 16 + q4 + j, 128, u * 2, f2bf(siluf_(acc[mt][j] + bias)));
  }
  __syncthreads();
  // w = h2@Wf3 + bf3
  {
    f32x4 acc[12];
    #pragma unroll
    for (int a = 0; a < 12; ++a) acc[a] = (f32x4){0.f, 0.f, 0.f, 0.f};
    for (int kc = 0; kc < 2; ++kc) {
      int cbyte = kc * 64 + cbl;
      #pragma unroll
      for (int mt = 0; mt < 4; ++mt) {
        bf16x8 a = ldb8(h2B, mt * 16 + l15, 128, cbyte);
        #pragma unroll
        for (int nt = 0; nt < 3; ++nt) {
          bf16x8 b = *(const bf16x8*)(wbf + FR_F3 + ((size_t)(wv * 3 + nt) * 2 + kc) * 512 + lane * 8);
          acc[mt * 3 + nt] = __builtin_amdgcn_mfma_f32_16x16x32_bf16(a, b, acc[mt * 3 + nt], 0, 0, 0);
        }
      }
    }
    __syncthreads();
    #pragma unroll
    for (int mt = 0; mt < 4; ++mt)
      #pragma unroll
      for (int nt = 0; nt < 3; ++nt) {
        int u = (wv * 3 + nt) * 16 + l15;
        float bias = bf3[u];
        #pragma unroll
        for (int j = 0; j < 4; ++j) {
          int e = mt * 16 + q4 + j;
          *(u16*)(wB + e * 384 + u * 2) = f2bf(acc[mt * 3 + nt][j] + bias);
        }
      }
  }
  __syncthreads();
  // gating
  for (int o = t; o < 64 * 128; o += 256) {
    int e = o >> 7, u = o & 127;
    float os = (e < nE) ? bf2f(outsG[(size_t)(e0 + e) * 192 + u]) : 0.f;
    float wv_ = bf2f(*(const u16*)(wB + e * 384 + u * 2));
    stb(zsA, e, 256, u * 2, f2bf(siluf_(os) * wv_));
  }
  for (int o = t; o < 192 * 64; o += 256) {
    int r = o >> 6, u = o & 63;
    int m = r >> 6, e = r & 63;
    float ov = 0.f, gate = 0.f, wv_ = 0.f;
    if (e < nE) {
      ov = bf2f(outvG[(size_t)(e0 + e) * 192 + m * 64 + u]);
      gate = sigmoidf_(bf2f(outsG[(size_t)(e0 + e) * 192 + 128 + u]));
      wv_ = bf2f(*(const u16*)(wB + e * 384 + (128 + u) * 2));
    }
    stb(zvA, r, 128, u * 2, f2bf(ov * gate * wv_));
  }
  __syncthreads();
  // post0
  {
    f32x4 acc[8];
    #pragma unroll
    for (int a = 0; a < 8; ++a) acc[a] = (f32x4){0.f, 0.f, 0.f, 0.f};
    for (int kc = 0; kc < 4; ++kc) {
      int cbyte = kc * 64 + cbl;
      #pragma unroll
      for (int nt = 0; nt < 2; ++nt) {
        bf16x8 b = *(const bf16x8*)(wbf + FR_P0 + ((size_t)(wv * 2 + nt) * 4 + kc) * 512 + lane * 8);
        #pragma unroll
        for (int mt = 0; mt < 4; ++mt) {
          bf16x8 a = ldb8(zsA, mt * 16 + l15, 256, cbyte);
          acc[mt * 2 + nt] = __builtin_amdgcn_mfma_f32_16x16x32_bf16(a, b, acc[mt * 2 + nt], 0, 0, 0);
        }
      }
    }
    #pragma unroll
    for (int mt = 0; mt < 4; ++mt)
      #pragma unroll
      for (int nt = 0; nt < 2; ++nt) {
        int u = (wv * 2 + nt) * 16 + l15;
        float bias = bpost0[u];
        #pragma unroll
        for (int j = 0; j < 4; ++j) {
          int e = mt * 16 + q4 + j;
          if (e < nE) {
            size_t o = (size_t)(e0 + e) * DIM + u;
            out[o] = out[o] + acc[mt * 2 + nt][j] + bias;
          }
        }
      }
  }
  // post1
  {
    f32x4 acc[12];
    #pragma unroll
    for (int a = 0; a < 12; ++a) acc[a] = (f32x4){0.f, 0.f, 0.f, 0.f};
    for (int kc = 0; kc < 2; ++kc) {
      int cbyte = kc * 64 + cbl;
      bf16x8 b = *(const bf16x8*)(wbf + FR_P1 + ((size_t)wv * 2 + kc) * 512 + lane * 8);
      #pragma unroll
      for (int mt = 0; mt < 12; ++mt) {
        bf16x8 a = ldb8(zvA, mt * 16 + l15, 128, cbyte);
        acc[mt] = __builtin_amdgcn_mfma_f32_16x16x32_bf16(a, b, acc[mt], 0, 0, 0);
      }
    }
    int u = wv * 16 + l15;
    #pragma unroll
    for (int mt = 0; mt < 12; ++mt)
      #pragma unroll
      for (int j = 0; j < 4; ++j) {
        int r = mt * 16 + q4 + j;
        int m = r >> 6, e = r & 63;
        if (e < nE) {
          size_t o = (size_t)(e0 + e) * DIM + 128 + u * 3 + m;
          out[o] = out[o] + acc[mt][j];
        }
      }
  }
}

// ---------------- K3: group statistics ----------------
__global__ __launch_bounds__(256) void k_stats(
    const float* __restrict__ out, const int* __restrict__ eidx,
    const int* __restrict__ batch, float* __restrict__ stats) {
  __shared__ float gacc[16][4];
  const int t = threadIdx.x;
  if (t < 64) ((float*)gacc)[t] = 0.0f;
  __syncthreads();
  const int el = t >> 4, l = t & 15;
  for (int ebase = blockIdx.x * 16; ebase < E_TOT; ebase += gridDim.x * 16) {
    int e = ebase + el;
    const float* z = out + (size_t)e * DIM;
    float s1 = 0, s2 = 0, s2v = 0;
    for (int c = l; c < 128; c += 16) { float x = z[c]; s1 += x; s2 += x * x; }
    for (int c = 128 + l; c < DIM; c += 16) { float x = z[c]; s2v += x * x; }
    #pragma unroll
    for (int msk = 8; msk; msk >>= 1) {
      s1 += __shfl_xor(s1, msk);
      s2 += __shfl_xor(s2, msk);
      s2v += __shfl_xor(s2v, msk);
    }
    if (l == 0) {
      int g = batch[eidx[e]];
      atomicAdd(&gacc[g][0], 1.0f);
      atomicAdd(&gacc[g][1], s1);
      atomicAdd(&gacc[g][2], s2);
      atomicAdd(&gacc[g][3], s2v);
    }
  }
  __syncthreads();
  if (t < 64) {
    float v = gacc[t >> 2][t & 3];
    if (v != 0.0f) atomicAdd(&stats[(t >> 2) * 16 + (t & 3)], v);
  }
}

// ---------------- K4: normalize + residual ----------------
__global__ __launch_bounds__(256) void k_norm(
    const float* __restrict__ edge_fea, const int* __restrict__ eidx,
    const int* __restrict__ batch, const float* __restrict__ stats,
    const float* __restrict__ gamma_s, const float* __restrict__ beta_s,
    const float* __restrict__ gamma_v, float* __restrict__ out) {
  __shared__ float meanL[16], invsL[16], invvL[16];
  __shared__ int gL[ET];
  const int t = threadIdx.x;
  const int e0 = blockIdx.x * ET;
  if (t < 16) {
    float cnt = fmaxf(stats[t * 16 + 0], 1.0f);
    float m = stats[t * 16 + 1] / (cnt * 128.0f);
    float var = stats[t * 16 + 2] / (cnt * 128.0f) - m * m;
    meanL[t] = m;
    invsL[t] = rsqrtf(var + 1e-5f);
    invvL[t] = rsqrtf(stats[t * 16 + 3] / (cnt * 192.0f) + 1e-5f);
  }
  if (t >= 32 && t < 32 + ET) gL[t - 32] = batch[eidx[e0 + t - 32]];
  __syncthreads();
  for (int o = t; o < ET * DIM; o += 256) {
    int e = o / DIM, c = o % DIM;
    int g = gL[e];
    size_t idx = (size_t)(e0 + e) * DIM + c;
    float z = out[idx];
    float r;
    if (c < 128) r = (z - meanL[g]) * invsL[g] * gamma_s[c] + beta_s[c];
    else r = z * invvL[g] * gamma_v[(c - 128) / 3];
    out[idx] = r + edge_fea[idx];
  }
}

extern "C" void kernel_launch(void* const* d_in, const int* in_sizes, int n_in,
                              void* d_out, int out_size, void* d_ws, size_t ws_size,
                              hipStream_t stream) {
  const float* node_fea = (const float*)d_in[0];
  const float* edge_oh  = (const float*)d_in[1];
  const float* edge_sh  = (const float*)d_in[2];
  const float* edge_fea = (const float*)d_in[3];
  const float* elen     = (const float*)d_in[4];
  const int*   eidx     = (const int*)d_in[5];
  const int*   batch    = (const int*)d_in[6];
  const float* Wsc_s    = (const float*)d_in[7];
  const float* Wsc_v    = (const float*)d_in[8];
  const float* Wpre0    = (const float*)d_in[9];
  const float* bpre0    = (const float*)d_in[10];
  const float* Wpre1    = (const float*)d_in[11];
  const float* Wss      = (const float*)d_in[12];
  const float* Wvs      = (const float*)d_in[13];
  const float* Wsv      = (const float*)d_in[14];
  const float* Wvv      = (const float*)d_in[15];
  const float* Wf1      = (const float*)d_in[16];
  const float* bf1      = (const float*)d_in[17];
  const float* Wf2      = (const float*)d_in[18];
  const float* bf2      = (const float*)d_in[19];
  const float* Wf3      = (const float*)d_in[20];
  const float* bf3      = (const float*)d_in[21];
  const float* Wpost0   = (const float*)d_in[22];
  const float* bpost0   = (const float*)d_in[23];
  const float* Wpost1   = (const float*)d_in[24];
  const float* gamma_s  = (const float*)d_in[25];
  const float* beta_s   = (const float*)d_in[26];
  const float* gamma_v  = (const float*)d_in[27];
  float* out = (float*)d_out;

  char* ws = (char*)d_ws;
  float* stats = (float*)ws;
  u16* wbf = (u16*)(ws + OFF_WBF);

  const int nblk64 = (E_TOT + MEs - 1) / MEs;  // 1563

  hipMemsetAsync(stats, 0, 16 * 16 * sizeof(float), stream);
  k_prep<<<(FR_END + 255) / 256, 256, 0, stream>>>(
      Wsc_s, Wsc_v, Wpre0, Wpre1, Wss, Wvs, Wsv, Wvv,
      Wf1, Wf2, Wf3, Wpost0, Wpost1, wbf);
  k_sc_s<<<nblk64, 256, 0, stream>>>(edge_fea, edge_oh, wbf, out);
  k_sc_v<<<nblk64, 256, 0, stream>>>(edge_fea, edge_oh, wbf + C0, out);
  u16* outsG = (u16*)(ws + OFF_OUTS);
  u16* outvG = (u16*)(ws + OFF_OUTV);
  k2a<<<nblk64, 512, 0, stream>>>(node_fea, edge_sh, edge_fea, eidx,
                                  wbf, bpre0, outsG, outvG);
  k2b<<<nblk64, 256, 0, stream>>>(elen, wbf, bf1, bf2, bf3, bpost0,
                                  outsG, outvG, out);
  k_stats<<<512, 256, 0, stream>>>(out, eidx, batch, stats);
  k_norm<<<E_TOT / ET, 256, 0, stream>>>(edge_fea, eidx, batch, stats,
                                         gamma_s, beta_s, gamma_v, out);
}

// Round 6
// 760.144 us; speedup vs baseline: 3.2496x; 1.4143x over previous
//
#include <hip/hip_runtime.h>
#include <math.h>

typedef unsigned int u32;
typedef unsigned short u16;
typedef __attribute__((ext_vector_type(8))) short bf16x8;
typedef __attribute__((ext_vector_type(4))) float f32x4;

#define E_TOT 100000
constexpr int NS = 128, DIM = 320;

constexpr float SC_S_SCALE = 0.022097086912079608f;  // 1/sqrt(128*16)
constexpr float SC_V_SCALE = 0.03125f;               // 1/32
constexpr float INV_SQRT128 = 0.08838834764831845f;
constexpr float INV_8 = 0.125f;
constexpr float INV_S384 = 0.05103103630798288f;
constexpr float INV_24 = 0.041666666666666664f;
constexpr float INV_S192 = 0.07216878364870323f;
constexpr float RSQRT2 = 0.7071067811865476f;

#define MFMA __builtin_amdgcn_mfma_f32_16x16x32_bf16
#define F4Z (f32x4){0.f, 0.f, 0.f, 0.f}

__device__ __forceinline__ float sigmoidf_(float x) { return 1.0f / (1.0f + __expf(-x)); }
__device__ __forceinline__ float siluf_(float x) { return x * sigmoidf_(x); }
__device__ __forceinline__ float bf2f(u16 h) {
  u32 u = ((u32)h) << 16;
  return __builtin_bit_cast(float, u);
}
__device__ __forceinline__ u16 f2bf(float f) {
  u32 u = __builtin_bit_cast(u32, f);
  return (u16)((u + 0x7fffu + ((u >> 16) & 1u)) >> 16);
}
__device__ __forceinline__ void gl_lds16(const void* g, void* l) {
  __builtin_amdgcn_global_load_lds((const __attribute__((address_space(1))) u32*)g,
                                   (__attribute__((address_space(3))) u32*)l, 16, 0, 0);
}
__device__ __forceinline__ bf16x8 pack8(float4 r0, float4 r1, float s) {
  bf16x8 a;
  a[0] = (short)f2bf(r0.x * s); a[1] = (short)f2bf(r0.y * s);
  a[2] = (short)f2bf(r0.z * s); a[3] = (short)f2bf(r0.w * s);
  a[4] = (short)f2bf(r1.x * s); a[5] = (short)f2bf(r1.y * s);
  a[6] = (short)f2bf(r1.z * s); a[7] = (short)f2bf(r1.w * s);
  return a;
}
// swizzled bf16 LDS helpers (XOR byte bits 4-6 with row&7); rowB multiple of 128
__device__ __forceinline__ void stb(char* base, int row, int rowB, int colByte, u16 v) {
  *(u16*)(base + row * rowB + (colByte ^ ((row & 7) << 4))) = v;
}
__device__ __forceinline__ u16 ldbs(const char* base, int row, int rowB, int colByte) {
  return *(const u16*)(base + row * rowB + (colByte ^ ((row & 7) << 4)));
}
__device__ __forceinline__ bf16x8 ldb8(const char* base, int row, int rowB, int colByte) {
  return *(const bf16x8*)(base + row * rowB + (colByte ^ ((row & 7) << 4)));
}
__device__ __forceinline__ void stb16(char* base, int row, int rowB, int colByte, bf16x8 v) {
  *(bf16x8*)(base + row * rowB + (colByte ^ ((row & 7) << 4))) = v;
}
// scale elements by sh1[(m0+j)%3]
__device__ __forceinline__ bf16x8 scale8_sh1(bf16x8 v, int m0, float t0, float t1, float t2) {
  float x0 = (m0 == 0) ? t0 : ((m0 == 1) ? t1 : t2);
  float x1 = (m0 == 0) ? t1 : ((m0 == 1) ? t2 : t0);
  float x2 = (m0 == 0) ? t2 : ((m0 == 1) ? t0 : t1);
  bf16x8 r;
  r[0] = (short)f2bf(bf2f((u16)v[0]) * x0); r[1] = (short)f2bf(bf2f((u16)v[1]) * x1);
  r[2] = (short)f2bf(bf2f((u16)v[2]) * x2); r[3] = (short)f2bf(bf2f((u16)v[3]) * x0);
  r[4] = (short)f2bf(bf2f((u16)v[4]) * x1); r[5] = (short)f2bf(bf2f((u16)v[5]) * x2);
  r[6] = (short)f2bf(bf2f((u16)v[6]) * x0); r[7] = (short)f2bf(bf2f((u16)v[7]) * x1);
  return r;
}

// ---------------- weight arena (element offsets) ----------------
#define OW_W2S   0        /* [128 u][2048 k=s*128+v]  (sc_s, R2 layout) */
#define OW_BTV   262144   /* [64 u][1024 k=s*64+v]    (sc_v, R2 layout) */
// fragment-linear: elem = (nt*(K/32)+kc)*512 + lane*8 + j
#define OW_PRE0  327680   /* N=128 K=128 */
#define OW_PRE1X 344064   /* N=192 K=192 block-diag */
#define OW_SS    380928   /* N=192 K=384 */
#define OW_VSX   454656   /* N=192 K=576 replicated (sh1 via A) */
#define OW_SV    565248   /* N=64  K=384 */
#define OW_VVX   589824   /* N=192 K=576 block-diag */
#define OW_F1    700416   /* N=64  K=128 */
#define OW_F2    708608   /* N=64  K=64  */
#define OW_F3    712704   /* N=192 K=64  */
#define OW_P0    724992   /* N=128 K=128 */
#define OW_P1X   741376   /* N=192 K=192 block-diag */
#define OW_END   778240

// ---------------- K0: weight prep ----------------
__device__ __forceinline__ void frag_uc(int oo, int K, int& up, int& c) {
  int per = (K >> 5) << 9;
  int nt = oo / per, r = oo % per;
  int kc = r >> 9, r2 = r & 511;
  int ln = r2 >> 3, j = r2 & 7;
  up = nt * 16 + (ln & 15);
  c = kc * 32 + (ln >> 4) * 8 + j;
}

__global__ __launch_bounds__(256) void k_prep(
    const float* __restrict__ Wsc_s, const float* __restrict__ Wsc_v,
    const float* __restrict__ Wpre0, const float* __restrict__ Wpre1,
    const float* __restrict__ Wss, const float* __restrict__ Wvs,
    const float* __restrict__ Wsv, const float* __restrict__ Wvv,
    const float* __restrict__ Wf1, const float* __restrict__ Wf2,
    const float* __restrict__ Wf3, const float* __restrict__ Wpost0,
    const float* __restrict__ Wpost1, u16* __restrict__ dst) {
  int o = blockIdx.x * 256 + threadIdx.x;
  if (o >= OW_END) return;
  float v;
  int up, c;
  if (o < OW_BTV) {
    int u = o >> 11, k = o & 2047, s = k >> 7, vv = k & 127;
    v = Wsc_s[((size_t)(vv * 16 + s)) * 128 + u];
  } else if (o < OW_PRE0) {
    int oo = o - OW_BTV; int u = oo >> 10, k = oo & 1023, s = k >> 6, vv = k & 63;
    v = Wsc_v[((size_t)(vv * 16 + s)) * 64 + u];
  } else if (o < OW_PRE1X) {
    frag_uc(o - OW_PRE0, 128, up, c);
    v = Wpre0[c * 128 + up] * INV_SQRT128;
  } else if (o < OW_SS) {
    frag_uc(o - OW_PRE1X, 192, up, c);
    int u = up / 3, m = up % 3, vv = c / 3, mp = c % 3;
    v = (m == mp) ? Wpre1[vv * 64 + u] * INV_8 : 0.f;
  } else if (o < OW_VSX) {
    frag_uc(o - OW_SS, 384, up, c);
    v = Wss[c * 192 + up] * (INV_S384 * RSQRT2);
  } else if (o < OW_SV) {
    frag_uc(o - OW_VSX, 576, up, c);
    int p = c / 192, r = c % 192, K = p * 64 + r / 3;
    v = Wvs[K * 192 + up] * (INV_24 * RSQRT2);
  } else if (o < OW_VVX) {
    frag_uc(o - OW_SV, 384, up, c);
    v = Wsv[c * 64 + up] * (INV_S384 * RSQRT2);
  } else if (o < OW_F1) {
    frag_uc(o - OW_VVX, 576, up, c);
    int u = up / 3, m = up % 3, p = c / 192, r = c % 192, vv = r / 3, mp = r % 3;
    v = (m == mp) ? Wvv[(p * 64 + vv) * 64 + u] * (INV_S192 * RSQRT2) : 0.f;
  } else if (o < OW_F2) {
    frag_uc(o - OW_F1, 128, up, c);
    v = Wf1[c * 64 + up];
  } else if (o < OW_F3) {
    frag_uc(o - OW_F2, 64, up, c);
    v = Wf2[c * 64 + up];
  } else if (o < OW_P0) {
    frag_uc(o - OW_F3, 64, up, c);
    v = Wf3[c * 192 + up];
  } else if (o < OW_P1X) {
    frag_uc(o - OW_P0, 128, up, c);
    v = Wpost0[c * 128 + up] * INV_SQRT128;
  } else {
    frag_uc(o - OW_P1X, 192, up, c);
    int u = up / 3, m = up % 3, vv = c / 3, mp = c % 3;
    v = (m == mp) ? Wpost1[vv * 64 + u] * INV_8 : 0.f;
  }
  dst[o] = f2bf(v);
}

// ---------------- K1a: sc_s via MFMA (verified R2) ----------------
#define MEs 64
__global__ __launch_bounds__(256, 2) void k_sc_s(
    const float* __restrict__ edge_fea, const float* __restrict__ ohp,
    const u16* __restrict__ W2s, float* __restrict__ out) {
  __shared__ u16 esB[64][136];
  __shared__ float ohL[64][16];
  __shared__ u16 Abuf[64 * 128];
  __shared__ u16 Bbuf[128 * 128];
  const int t = threadIdx.x;
  const int lane = t & 63, ww = t >> 6;
  const int e0 = blockIdx.x * MEs;
  const int nE = min(MEs, E_TOT - e0);

  for (int o = t; o < 64 * 32; o += 256) {
    int e = o >> 5, c4 = (o & 31) << 2;
    float4 x = (e < nE) ? *(const float4*)&edge_fea[(size_t)(e0 + e) * DIM + c4]
                        : make_float4(0.f, 0.f, 0.f, 0.f);
    esB[e][c4 + 0] = f2bf(x.x); esB[e][c4 + 1] = f2bf(x.y);
    esB[e][c4 + 2] = f2bf(x.z); esB[e][c4 + 3] = f2bf(x.w);
  }
  for (int o = t; o < 64 * 16; o += 256) {
    int e = o >> 4, s = o & 15;
    ohL[e][s] = (e < nE) ? ohp[(size_t)(e0 + e) * 16 + s] : 0.f;
  }
  __syncthreads();

  f32x4 acc[4][2];
  #pragma unroll
  for (int a = 0; a < 4; ++a)
    #pragma unroll
    for (int b = 0; b < 2; ++b) acc[a][b] = F4Z;

  for (int s = 0; s < 16; ++s) {
    {
      const char* sb = (const char*)W2s + s * 256;
      #pragma unroll
      for (int it = 0; it < 8; ++it) {
        int n = it * 256 + t;
        int u = n >> 4, gp = n & 15, g = gp ^ (u & 7);
        gl_lds16(sb + (size_t)u * 4096 + g * 16, (char*)Bbuf + n * 16);
      }
    }
    #pragma unroll
    for (int it = 0; it < 4; ++it) {
      int n = it * 256 + t;
      int e = n >> 4, gp = n & 15, g = gp ^ (e & 7);
      float ohs = ohL[e][s];
      union { uint4 q; u16 h[8]; } in, ov;
      in.q = *(const uint4*)&esB[e][g * 8];
      #pragma unroll
      for (int j = 0; j < 8; ++j) ov.h[j] = f2bf(bf2f(in.h[j]) * ohs);
      *(uint4*)((char*)Abuf + e * 256 + gp * 16) = ov.q;
    }
    __syncthreads();

    const int cbl = (lane >> 4) << 4;
    #pragma unroll
    for (int ks = 0; ks < 4; ++ks) {
      int cbyte = ks * 64 + cbl;
      bf16x8 bfr[2], afr[4];
      #pragma unroll
      for (int ct = 0; ct < 2; ++ct) {
        int u = ww * 32 + ct * 16 + (lane & 15);
        bfr[ct] = *(const bf16x8*)((const char*)Bbuf + u * 256 + (cbyte ^ ((u & 7) << 4)));
      }
      #pragma unroll
      for (int rt = 0; rt < 4; ++rt) {
        int e = rt * 16 + (lane & 15);
        afr[rt] = *(const bf16x8*)((const char*)Abuf + e * 256 + (cbyte ^ ((e & 7) << 4)));
      }
      #pragma unroll
      for (int rt = 0; rt < 4; ++rt)
        #pragma unroll
        for (int ct = 0; ct < 2; ++ct)
          acc[rt][ct] = MFMA(afr[rt], bfr[ct], acc[rt][ct], 0, 0, 0);
    }
    __syncthreads();
  }

  #pragma unroll
  for (int rt = 0; rt < 4; ++rt) {
    int ebase = rt * 16 + ((lane >> 4) << 2);
    #pragma unroll
    for (int ct = 0; ct < 2; ++ct) {
      int u = ww * 32 + ct * 16 + (lane & 15);
      #pragma unroll
      for (int j = 0; j < 4; ++j) {
        int ee = ebase + j;
        if (ee < nE) out[(size_t)(e0 + ee) * DIM + u] = acc[rt][ct][j] * SC_S_SCALE;
      }
    }
  }
}

// ---------------- K1b: sc_v via MFMA (verified R2) ----------------
__global__ __launch_bounds__(256, 2) void k_sc_v(
    const float* __restrict__ edge_fea, const float* __restrict__ ohp,
    const u16* __restrict__ Btv, float* __restrict__ out) {
  __shared__ u16 evT[3][64][72];
  __shared__ float ohL[64][16];
  __shared__ u16 Abuf[192 * 64];
  __shared__ u16 Bbuf[64 * 64];
  const int t = threadIdx.x;
  const int lane = t & 63, ww = t >> 6;
  const int e0 = blockIdx.x * MEs;
  const int nE = min(MEs, E_TOT - e0);

  for (int o = t; o < 64 * 192; o += 256) {
    int e = o / 192, c = o % 192;
    int v = c / 3, m = c % 3;
    float x = (e < nE) ? edge_fea[(size_t)(e0 + e) * DIM + NS + c] : 0.f;
    evT[m][e][v] = f2bf(x);
  }
  for (int o = t; o < 64 * 16; o += 256) {
    int e = o >> 4, s = o & 15;
    ohL[e][s] = (e < nE) ? ohp[(size_t)(e0 + e) * 16 + s] : 0.f;
  }
  __syncthreads();

  f32x4 acc[12];
  #pragma unroll
  for (int a = 0; a < 12; ++a) acc[a] = F4Z;

  for (int s = 0; s < 16; ++s) {
    #pragma unroll
    for (int it = 0; it < 2; ++it) {
      int n = it * 256 + t;
      int u = n >> 3, gp = n & 7, g = gp ^ (u & 7);
      gl_lds16((const char*)Btv + (size_t)u * 2048 + s * 128 + g * 16, (char*)Bbuf + n * 16);
    }
    #pragma unroll
    for (int it = 0; it < 6; ++it) {
      int n = it * 256 + t;
      int r = n >> 3, gp = n & 7, g = gp ^ (r & 7);
      int e = r / 3, m = r - e * 3;
      float ohs = ohL[e][s];
      union { uint4 q; u16 h[8]; } in, ov;
      in.q = *(const uint4*)&evT[m][e][g * 8];
      #pragma unroll
      for (int j = 0; j < 8; ++j) ov.h[j] = f2bf(bf2f(in.h[j]) * ohs);
      *(uint4*)((char*)Abuf + r * 128 + gp * 16) = ov.q;
    }
    __syncthreads();

    const int cbl = (lane >> 4) << 4;
    #pragma unroll
    for (int ks = 0; ks < 2; ++ks) {
      int cbyte = ks * 64 + cbl;
      int u = ww * 16 + (lane & 15);
      bf16x8 bfr = *(const bf16x8*)((const char*)Bbuf + u * 128 + (cbyte ^ ((u & 7) << 4)));
      #pragma unroll
      for (int rt = 0; rt < 12; ++rt) {
        int r = rt * 16 + (lane & 15);
        bf16x8 afr = *(const bf16x8*)((const char*)Abuf + r * 128 + (cbyte ^ ((r & 7) << 4)));
        acc[rt] = MFMA(afr, bfr, acc[rt], 0, 0, 0);
      }
    }
    __syncthreads();
  }

  #pragma unroll
  for (int rt = 0; rt < 12; ++rt) {
    int rbase = rt * 16 + ((lane >> 4) << 2);
    int u = ww * 16 + (lane & 15);
    #pragma unroll
    for (int j = 0; j < 4; ++j) {
      int r = rbase + j;
      int e = r / 3, m = r - e * 3;
      if (e < nE) out[(size_t)(e0 + e) * DIM + NS + u * 3 + m] = acc[rt][j] * SC_V_SCALE;
    }
  }
}

// ---------------- K2: fused chain, M=32, 512 thr, 2 blocks/CU ----------------
// arena: [0,24K) sA0/1/2 -> wB/zsB/gateB ; [24K,60K) vA0/1/2 -> zvB ;
//        [60K,64K) t1B ; [64K,68K) hB(h1->h2) ; [68K,76K) elB ; +shF/ij
#define A_SZ 78592
__global__ __launch_bounds__(512, 4) void k_chain(
    const float* __restrict__ node_fea, const float* __restrict__ edge_sh,
    const float* __restrict__ edge_fea, const float* __restrict__ elen,
    const int* __restrict__ eidx, const u16* __restrict__ wbf,
    const float* __restrict__ bpre0, const float* __restrict__ bf1,
    const float* __restrict__ bf2, const float* __restrict__ bf3,
    const float* __restrict__ bpost0, float* __restrict__ out) {
  __shared__ char AR[A_SZ];
  float* shF = (float*)(AR + 77824);  // [32][4]
  int* ijL = (int*)(AR + 78336);      // [2][32]
  const int t = threadIdx.x, lane = t & 63, wv = t >> 6;
  const int l15 = lane & 15, q8 = lane >> 4, q4 = q8 << 2, cbl = q8 << 4;
  const int e0 = blockIdx.x * 32;

#define SA(b) (AR + (b) * 8192)
#define VA(b) (AR + 24576 + (b) * 12288)
  char* wB = AR;
  char* zsB = AR + 12288;
  char* gateB = AR + 20480;
  char* zvB = AR + 24576;
  char* t1B = AR + 61440;
  char* hB = AR + 65536;
  char* elB = AR + 69632;

  if (t < 64) { int p = t >> 5, e = t & 31; ijL[p * 32 + e] = eidx[p * E_TOT + e0 + e]; }
  if (t >= 64 && t < 192) { int o = t - 64; shF[o] = edge_sh[(size_t)e0 * 4 + o]; }
  __syncthreads();

  // ---- P0: staging (16B swizzled chunks) ----
  for (int o = t; o < 1280; o += 512) {
    int c = o % 40, e = o / 40;
    const float* src = edge_fea + (size_t)(e0 + e) * 320 + c * 8;
    float4 r0 = *(const float4*)src, r1 = *(const float4*)(src + 4);
    bf16x8 v = pack8(r0, r1, 1.f);
    if (c < 16) stb16(SA(2), e, 256, c * 16, v);
    else        stb16(VA(2), e, 384, (c - 16) * 16, v);
  }
  for (int o = t; o < 2560; o += 512) {
    int c = o % 40, tmp = o / 40, e = tmp & 31, p = tmp >> 5;
    const float* src = node_fea + (size_t)ijL[p * 32 + e] * 320 + c * 8;
    float4 r0 = *(const float4*)src, r1 = *(const float4*)(src + 4);
    bf16x8 v = pack8(r0, r1, 1.f);
    if (c < 16) stb16(SA(p), e, 256, c * 16, v);
    else        stb16(VA(p), e, 384, (c - 16) * 16, v);
  }
  for (int o = t; o < 512; o += 512) {
    int c = o & 15, e = o >> 4;
    const float* src = elen + (size_t)(e0 + e) * 128 + c * 8;
    float4 r0 = *(const float4*)src, r1 = *(const float4*)(src + 4);
    stb16(elB, e, 256, c * 16, pack8(r0, r1, 1.f));
  }
  __syncthreads();

  // ---- P1: v-pre (w0-3) | s-pre (w4-5) | h1 (w6-7) ----
  f32x4 acc[8];
  #pragma unroll
  for (int a = 0; a < 8; ++a) acc[a] = F4Z;
  if (wv < 4) {
    for (int kc = 0; kc < 6; ++kc) {
      bf16x8 a0 = ldb8(VA(2), l15, 384, kc * 64 + cbl);
      bf16x8 a1 = ldb8(VA(2), 16 + l15, 384, kc * 64 + cbl);
      #pragma unroll
      for (int i = 0; i < 3; ++i) {
        int nt = wv * 3 + i;
        bf16x8 b = *(const bf16x8*)(wbf + OW_PRE1X + (((size_t)nt * 6 + kc) << 9) + lane * 8);
        acc[i] = MFMA(a0, b, acc[i], 0, 0, 0);
        acc[3 + i] = MFMA(a1, b, acc[3 + i], 0, 0, 0);
      }
    }
  } else if (wv < 6) {
    for (int kc = 0; kc < 4; ++kc) {
      bf16x8 a0 = ldb8(SA(2), l15, 256, kc * 64 + cbl);
      bf16x8 a1 = ldb8(SA(2), 16 + l15, 256, kc * 64 + cbl);
      #pragma unroll
      for (int i = 0; i < 4; ++i) {
        int nt = (wv - 4) * 4 + i;
        bf16x8 b = *(const bf16x8*)(wbf + OW_PRE0 + (((size_t)nt * 4 + kc) << 9) + lane * 8);
        acc[i] = MFMA(a0, b, acc[i], 0, 0, 0);
        acc[4 + i] = MFMA(a1, b, acc[4 + i], 0, 0, 0);
      }
    }
  } else {
    for (int kc = 0; kc < 4; ++kc) {
      bf16x8 a0 = ldb8(elB, l15, 256, kc * 64 + cbl);
      bf16x8 a1 = ldb8(elB, 16 + l15, 256, kc * 64 + cbl);
      #pragma unroll
      for (int i = 0; i < 2; ++i) {
        int nt = (wv - 6) * 2 + i;
        bf16x8 b = *(const bf16x8*)(wbf + OW_F1 + (((size_t)nt * 4 + kc) << 9) + lane * 8);
        acc[i] = MFMA(a0, b, acc[i], 0, 0, 0);
        acc[2 + i] = MFMA(a1, b, acc[2 + i], 0, 0, 0);
      }
    }
  }
  __syncthreads();  // BAR1a
  if (wv < 4) {
    #pragma unroll
    for (int mt = 0; mt < 2; ++mt)
      #pragma unroll
      for (int i = 0; i < 3; ++i) {
        int up = (wv * 3 + i) * 16 + l15;
        #pragma unroll
        for (int j = 0; j < 4; ++j)
          stb(VA(2), mt * 16 + q4 + j, 384, up * 2, f2bf(acc[mt * 3 + i][j]));
      }
  } else if (wv < 6) {
    #pragma unroll
    for (int i = 0; i < 4; ++i) {
      int u = ((wv - 4) * 4 + i) * 16 + l15;
      float bias = bpre0[u];
      #pragma unroll
      for (int mt = 0; mt < 2; ++mt)
        #pragma unroll
        for (int j = 0; j < 4; ++j)
          stb(SA(2), mt * 16 + q4 + j, 256, u * 2, f2bf(acc[mt * 4 + i][j] + bias));
    }
  } else {
    #pragma unroll
    for (int i = 0; i < 2; ++i) {
      int u = ((wv - 6) * 2 + i) * 16 + l15;
      float bias = bf1[u];
      #pragma unroll
      for (int mt = 0; mt < 2; ++mt)
        #pragma unroll
        for (int j = 0; j < 4; ++j)
          stb(hB, mt * 16 + q4 + j, 128, u * 2, f2bf(siluf_(acc[mt * 2 + i][j] + bias)));
    }
  }
  __syncthreads();  // BAR1b

  // ---- P2: out_s (w0-5, acc4) | t1 (w6-7, acc4) ; h2 (all, acc1) ----
  f32x4 os[4] = {F4Z, F4Z, F4Z, F4Z};
  f32x4 h2a = F4Z;
  {
    const int hmt = wv >> 2, hnt = wv & 3;
    #pragma unroll
    for (int kc = 0; kc < 2; ++kc) {
      bf16x8 a = ldb8(hB, hmt * 16 + l15, 128, kc * 64 + cbl);
      bf16x8 b = *(const bf16x8*)(wbf + OW_F2 + (((size_t)hnt * 2 + kc) << 9) + lane * 8);
      h2a = MFMA(a, b, h2a, 0, 0, 0);
    }
  }
  if (wv < 6) {
    for (int kc = 0; kc < 12; ++kc) {
      int buf = kc >> 2, cB = (kc & 3) * 64 + cbl;
      bf16x8 a0 = ldb8(SA(buf), l15, 256, cB);
      bf16x8 a1 = ldb8(SA(buf), 16 + l15, 256, cB);
      #pragma unroll
      for (int i = 0; i < 2; ++i) {
        int nt = wv * 2 + i;
        bf16x8 b = *(const bf16x8*)(wbf + OW_SS + (((size_t)nt * 12 + kc) << 9) + lane * 8);
        os[i] = MFMA(a0, b, os[i], 0, 0, 0);
        os[2 + i] = MFMA(a1, b, os[2 + i], 0, 0, 0);
      }
    }
    #pragma unroll
    for (int mt = 0; mt < 2; ++mt)
      #pragma unroll
      for (int i = 0; i < 2; ++i)
        #pragma unroll
        for (int j = 0; j < 4; ++j)
          os[mt * 2 + i][j] *= shF[(mt * 16 + q4 + j) * 4 + 0];
    float sa0 = shF[l15 * 4 + 1], sa1 = shF[l15 * 4 + 2], sa2 = shF[l15 * 4 + 3];
    float sb0 = shF[(16 + l15) * 4 + 1], sb1 = shF[(16 + l15) * 4 + 2], sb2 = shF[(16 + l15) * 4 + 3];
    for (int p = 0; p < 3; ++p)
      for (int kc6 = 0; kc6 < 6; ++kc6) {
        int cB = kc6 * 64 + cbl;
        int m0 = (2 * (kc6 + q8)) % 3;
        bf16x8 a0 = scale8_sh1(ldb8(VA(p), l15, 384, cB), m0, sa0, sa1, sa2);
        bf16x8 a1 = scale8_sh1(ldb8(VA(p), 16 + l15, 384, cB), m0, sb0, sb1, sb2);
        int kcg = p * 6 + kc6;
        #pragma unroll
        for (int i = 0; i < 2; ++i) {
          int nt = wv * 2 + i;
          bf16x8 b = *(const bf16x8*)(wbf + OW_VSX + (((size_t)nt * 18 + kcg) << 9) + lane * 8);
          os[i] = MFMA(a0, b, os[i], 0, 0, 0);
          os[2 + i] = MFMA(a1, b, os[2 + i], 0, 0, 0);
        }
      }
  } else {
    for (int kc = 0; kc < 12; ++kc) {
      int buf = kc >> 2, cB = (kc & 3) * 64 + cbl;
      bf16x8 a0 = ldb8(SA(buf), l15, 256, cB);
      bf16x8 a1 = ldb8(SA(buf), 16 + l15, 256, cB);
      #pragma unroll
      for (int i = 0; i < 2; ++i) {
        int nt = (wv - 6) * 2 + i;
        bf16x8 b = *(const bf16x8*)(wbf + OW_SV + (((size_t)nt * 12 + kc) << 9) + lane * 8);
        os[i] = MFMA(a0, b, os[i], 0, 0, 0);   // reuse os[] as t1 acc for w6-7
        os[2 + i] = MFMA(a1, b, os[2 + i], 0, 0, 0);
      }
    }
  }
  __syncthreads();  // BAR2a
  {  // h2 writeback (all waves)
    const int hmt = wv >> 2;
    int u = (wv & 3) * 16 + l15;
    float bias = bf2[u];
    #pragma unroll
    for (int j = 0; j < 4; ++j)
      stb(hB, hmt * 16 + q4 + j, 128, u * 2, f2bf(siluf_(h2a[j] + bias)));
  }
  if (wv >= 6) {  // t1 writeback
    #pragma unroll
    for (int mt = 0; mt < 2; ++mt)
      #pragma unroll
      for (int i = 0; i < 2; ++i) {
        int u = ((wv - 6) * 2 + i) * 16 + l15;
        #pragma unroll
        for (int j = 0; j < 4; ++j)
          stb(t1B, mt * 16 + q4 + j, 128, u * 2, f2bf(os[mt * 2 + i][j]));
      }
  }
  __syncthreads();  // BAR2b

  // ---- P3: w = h2@Wf3 + bf3 (all waves, 3 acc) ----
  {
    f32x4 wa[3] = {F4Z, F4Z, F4Z};
    const int mtw = wv >> 2;
    #pragma unroll
    for (int kc = 0; kc < 2; ++kc) {
      bf16x8 a = ldb8(hB, mtw * 16 + l15, 128, kc * 64 + cbl);
      #pragma unroll
      for (int i = 0; i < 3; ++i) {
        int nt = (wv & 3) * 3 + i;
        bf16x8 b = *(const bf16x8*)(wbf + OW_F3 + (((size_t)nt * 2 + kc) << 9) + lane * 8);
        wa[i] = MFMA(a, b, wa[i], 0, 0, 0);
      }
    }
    #pragma unroll
    for (int i = 0; i < 3; ++i) {
      int up = ((wv & 3) * 3 + i) * 16 + l15;
      float bias = bf3[up];
      #pragma unroll
      for (int j = 0; j < 4; ++j)
        stb(wB, mtw * 16 + q4 + j, 384, up * 2, f2bf(wa[i][j] + bias));
    }
  }
  __syncthreads();  // BAR3

  // ---- P4: gating (w0-5) + out_v MFMAs (all) ----
  if (wv < 6) {
    #pragma unroll
    for (int mt = 0; mt < 2; ++mt)
      #pragma unroll
      for (int i = 0; i < 2; ++i) {
        int up = (wv * 2 + i) * 16 + l15;
        #pragma unroll
        for (int j = 0; j < 4; ++j) {
          int e = mt * 16 + q4 + j;
          float w_ = bf2f(ldbs(wB, e, 384, up * 2));
          float o_ = os[mt * 2 + i][j];
          if (up < 128) stb(zsB, e, 256, up * 2, f2bf(siluf_(o_) * w_));
          else stb(gateB, e, 128, (up - 128) * 2, f2bf(sigmoidf_(o_) * w_));
        }
      }
  }
  f32x4 ov[3] = {F4Z, F4Z, F4Z};
  {
    const int mtv = wv >> 2;
    for (int p = 0; p < 3; ++p)
      for (int kc6 = 0; kc6 < 6; ++kc6) {
        int cB = kc6 * 64 + cbl;
        bf16x8 a = ldb8(VA(p), mtv * 16 + l15, 384, cB);
        int kcg = p * 6 + kc6;
        #pragma unroll
        for (int i = 0; i < 3; ++i) {
          int nt = (wv & 3) * 3 + i;
          bf16x8 b = *(const bf16x8*)(wbf + OW_VVX + (((size_t)nt * 18 + kcg) << 9) + lane * 8);
          ov[i] = MFMA(a, b, ov[i], 0, 0, 0);
        }
      }
  }
  __syncthreads();  // BAR4
  {
    const int mtv = wv >> 2;
    #pragma unroll
    for (int i = 0; i < 3; ++i) {
      int up = ((wv & 3) * 3 + i) * 16 + l15;
      int u = (up * 683) >> 11, m = up - 3 * u;
      #pragma unroll
      for (int j = 0; j < 4; ++j) {
        int e = mtv * 16 + q4 + j;
        float t1v = bf2f(ldbs(t1B, e, 128, u * 2));
        float g = bf2f(ldbs(gateB, e, 128, u * 2));
        float val = ov[i][j] * shF[e * 4 + 0] + t1v * shF[e * 4 + 1 + m];
        stb(zvB, e, 384, up * 2, f2bf(val * g));
      }
    }
  }
  __syncthreads();  // BAR5

  // ---- P5: post0 + post1, RMW onto sc in d_out ----
  {
    f32x4 p0[2] = {F4Z, F4Z};
    #pragma unroll
    for (int kc = 0; kc < 4; ++kc) {
      int cB = kc * 64 + cbl;
      bf16x8 a0 = ldb8(zsB, l15, 256, cB);
      bf16x8 a1 = ldb8(zsB, 16 + l15, 256, cB);
      bf16x8 b = *(const bf16x8*)(wbf + OW_P0 + (((size_t)wv * 4 + kc) << 9) + lane * 8);
      p0[0] = MFMA(a0, b, p0[0], 0, 0, 0);
      p0[1] = MFMA(a1, b, p0[1], 0, 0, 0);
    }
    int u = wv * 16 + l15;
    float bias = bpost0[u];
    #pragma unroll
    for (int mt = 0; mt < 2; ++mt)
      #pragma unroll
      for (int j = 0; j < 4; ++j) {
        size_t o = (size_t)(e0 + mt * 16 + q4 + j) * DIM + u;
        out[o] = out[o] + p0[mt][j] + bias;
      }
  }
  {
    f32x4 p1[3] = {F4Z, F4Z, F4Z};
    const int mtv = wv >> 2;
    #pragma unroll
    for (int kc = 0; kc < 6; ++kc) {
      int cB = kc * 64 + cbl;
      bf16x8 a = ldb8(zvB, mtv * 16 + l15, 384, cB);
      #pragma unroll
      for (int i = 0; i < 3; ++i) {
        int nt = (wv & 3) * 3 + i;
        bf16x8 b = *(const bf16x8*)(wbf + OW_P1X + (((size_t)nt * 6 + kc) << 9) + lane * 8);
        p1[i] = MFMA(a, b, p1[i], 0, 0, 0);
      }
    }
    #pragma unroll
    for (int i = 0; i < 3; ++i) {
      int up = ((wv & 3) * 3 + i) * 16 + l15;
      #pragma unroll
      for (int j = 0; j < 4; ++j) {
        size_t o = (size_t)(e0 + mtv * 16 + q4 + j) * DIM + 128 + up;
        out[o] = out[o] + p1[i][j];
      }
    }
  }
#undef SA
#undef VA
}

// ---------------- K3: group statistics ----------------
__global__ __launch_bounds__(256) void k_stats(
    const float* __restrict__ out, const int* __restrict__ eidx,
    const int* __restrict__ batch, float* __restrict__ stats) {
  __shared__ float gacc[16][4];
  const int t = threadIdx.x;
  if (t < 64) ((float*)gacc)[t] = 0.0f;
  __syncthreads();
  const int el = t >> 4, l = t & 15;
  for (int ebase = blockIdx.x * 16; ebase < E_TOT; ebase += gridDim.x * 16) {
    int e = ebase + el;
    const float* z = out + (size_t)e * DIM;
    float s1 = 0, s2 = 0, s2v = 0;
    for (int c = l; c < 128; c += 16) { float x = z[c]; s1 += x; s2 += x * x; }
    for (int c = 128 + l; c < DIM; c += 16) { float x = z[c]; s2v += x * x; }
    #pragma unroll
    for (int msk = 8; msk; msk >>= 1) {
      s1 += __shfl_xor(s1, msk);
      s2 += __shfl_xor(s2, msk);
      s2v += __shfl_xor(s2v, msk);
    }
    if (l == 0) {
      int g = batch[eidx[e]];
      atomicAdd(&gacc[g][0], 1.0f);
      atomicAdd(&gacc[g][1], s1);
      atomicAdd(&gacc[g][2], s2);
      atomicAdd(&gacc[g][3], s2v);
    }
  }
  __syncthreads();
  if (t < 64) {
    float v = gacc[t >> 2][t & 3];
    if (v != 0.0f) atomicAdd(&stats[(t >> 2) * 16 + (t & 3)], v);
  }
}

// ---------------- K4: normalize + residual (float4) ----------------
__global__ __launch_bounds__(256) void k_norm(
    const float* __restrict__ edge_fea, const int* __restrict__ eidx,
    const int* __restrict__ batch, const float* __restrict__ stats,
    const float* __restrict__ gamma_s, const float* __restrict__ beta_s,
    const float* __restrict__ gamma_v, float* __restrict__ out) {
  __shared__ float meanL[16], invsL[16], invvL[16];
  __shared__ int gL[16];
  const int t = threadIdx.x;
  const int e0 = blockIdx.x * 16;
  if (t < 16) {
    float cnt = fmaxf(stats[t * 16 + 0], 1.0f);
    float m = stats[t * 16 + 1] / (cnt * 128.0f);
    float var = stats[t * 16 + 2] / (cnt * 128.0f) - m * m;
    meanL[t] = m;
    invsL[t] = rsqrtf(var + 1e-5f);
    invvL[t] = rsqrtf(stats[t * 16 + 3] / (cnt * 192.0f) + 1e-5f);
  }
  if (t >= 32 && t < 48) gL[t - 32] = batch[eidx[e0 + t - 32]];
  __syncthreads();
  for (int o = t; o < 16 * 80; o += 256) {
    int e = o / 80, q = o % 80;
    size_t idx = (size_t)(e0 + e) * 80 + q;
    float4 z = ((const float4*)out)[idx];
    float4 ef = ((const float4*)edge_fea)[idx];
    int g = gL[e];
    float4 r;
    if (q < 32) {
      int c = q * 4;
      r.x = (z.x - meanL[g]) * invsL[g] * gamma_s[c + 0] + beta_s[c + 0] + ef.x;
      r.y = (z.y - meanL[g]) * invsL[g] * gamma_s[c + 1] + beta_s[c + 1] + ef.y;
      r.z = (z.z - meanL[g]) * invsL[g] * gamma_s[c + 2] + beta_s[c + 2] + ef.z;
      r.w = (z.w - meanL[g]) * invsL[g] * gamma_s[c + 3] + beta_s[c + 3] + ef.w;
    } else {
      int cc = q * 4 - 128;
      r.x = z.x * invvL[g] * gamma_v[(cc + 0) / 3] + ef.x;
      r.y = z.y * invvL[g] * gamma_v[(cc + 1) / 3] + ef.y;
      r.z = z.z * invvL[g] * gamma_v[(cc + 2) / 3] + ef.z;
      r.w = z.w * invvL[g] * gamma_v[(cc + 3) / 3] + ef.w;
    }
    ((float4*)out)[idx] = r;
  }
}

extern "C" void kernel_launch(void* const* d_in, const int* in_sizes, int n_in,
                              void* d_out, int out_size, void* d_ws, size_t ws_size,
                              hipStream_t stream) {
  const float* node_fea = (const float*)d_in[0];
  const float* edge_oh  = (const float*)d_in[1];
  const float* edge_sh  = (const float*)d_in[2];
  const float* edge_fea = (const float*)d_in[3];
  const float* elen     = (const float*)d_in[4];
  const int*   eidx     = (const int*)d_in[5];
  const int*   batch    = (const int*)d_in[6];
  const float* Wsc_s    = (const float*)d_in[7];
  const float* Wsc_v    = (const float*)d_in[8];
  const float* Wpre0    = (const float*)d_in[9];
  const float* bpre0    = (const float*)d_in[10];
  const float* Wpre1    = (const float*)d_in[11];
  const float* Wss      = (const float*)d_in[12];
  const float* Wvs      = (const float*)d_in[13];
  const float* Wsv      = (const float*)d_in[14];
  const float* Wvv      = (const float*)d_in[15];
  const float* Wf1      = (const float*)d_in[16];
  const float* bf1      = (const float*)d_in[17];
  const float* Wf2      = (const float*)d_in[18];
  const float* bf2      = (const float*)d_in[19];
  const float* Wf3      = (const float*)d_in[20];
  const float* bf3      = (const float*)d_in[21];
  const float* Wpost0   = (const float*)d_in[22];
  const float* bpost0   = (const float*)d_in[23];
  const float* Wpost1   = (const float*)d_in[24];
  const float* gamma_s  = (const float*)d_in[25];
  const float* beta_s   = (const float*)d_in[26];
  const float* gamma_v  = (const float*)d_in[27];
  float* out = (float*)d_out;

  char* ws = (char*)d_ws;
  float* stats = (float*)ws;
  u16* wbf = (u16*)(ws + 1024);

  hipMemsetAsync(stats, 0, 16 * 16 * sizeof(float), stream);
  k_prep<<<(OW_END + 255) / 256, 256, 0, stream>>>(
      Wsc_s, Wsc_v, Wpre0, Wpre1, Wss, Wvs, Wsv, Wvv,
      Wf1, Wf2, Wf3, Wpost0, Wpost1, wbf);
  const int nblk64 = (E_TOT + MEs - 1) / MEs;  // 1563
  k_sc_s<<<nblk64, 256, 0, stream>>>(edge_fea, edge_oh, wbf + OW_W2S, out);
  k_sc_v<<<nblk64, 256, 0, stream>>>(edge_fea, edge_oh, wbf + OW_BTV, out);
  k_chain<<<E_TOT / 32, 512, 0, stream>>>(node_fea, edge_sh, edge_fea, elen, eidx,
                                          wbf, bpre0, bf1, bf2, bf3, bpost0, out);
  k_stats<<<512, 256, 0, stream>>>(out, eidx, batch, stats);
  k_norm<<<E_TOT / 16, 256, 0, stream>>>(edge_fea, eidx, batch, stats,
                                         gamma_s, beta_s, gamma_v, out);
}

// Round 7
// 659.226 us; speedup vs baseline: 3.7470x; 1.1531x over previous
//
#include <hip/hip_runtime.h>
#include <math.h>

typedef unsigned int u32;
typedef unsigned short u16;
typedef __attribute__((ext_vector_type(8))) short bf16x8;
typedef __attribute__((ext_vector_type(4))) float f32x4;

#define E_TOT 100000
constexpr int NS = 128, DIM = 320;

constexpr float SC_S_SCALE = 0.022097086912079608f;  // 1/sqrt(128*16)
constexpr float SC_V_SCALE = 0.03125f;               // 1/32
constexpr float INV_SQRT128 = 0.08838834764831845f;
constexpr float INV_8 = 0.125f;
constexpr float INV_S384 = 0.05103103630798288f;
constexpr float INV_24 = 0.041666666666666664f;
constexpr float INV_S192 = 0.07216878364870323f;
constexpr float RSQRT2 = 0.7071067811865476f;

#define MFMA __builtin_amdgcn_mfma_f32_16x16x32_bf16
#define F4Z (f32x4){0.f, 0.f, 0.f, 0.f}

__device__ __forceinline__ float sigmoidf_(float x) { return 1.0f / (1.0f + __expf(-x)); }
__device__ __forceinline__ float siluf_(float x) { return x * sigmoidf_(x); }
__device__ __forceinline__ float bf2f(u16 h) {
  u32 u = ((u32)h) << 16;
  return __builtin_bit_cast(float, u);
}
__device__ __forceinline__ u16 f2bf(float f) {
  u32 u = __builtin_bit_cast(u32, f);
  return (u16)((u + 0x7fffu + ((u >> 16) & 1u)) >> 16);
}
__device__ __forceinline__ void gl_lds16(const void* g, void* l) {
  __builtin_amdgcn_global_load_lds((const __attribute__((address_space(1))) u32*)g,
                                   (__attribute__((address_space(3))) u32*)l, 16, 0, 0);
}
__device__ __forceinline__ bf16x8 pack8(float4 r0, float4 r1, float s) {
  bf16x8 a;
  a[0] = (short)f2bf(r0.x * s); a[1] = (short)f2bf(r0.y * s);
  a[2] = (short)f2bf(r0.z * s); a[3] = (short)f2bf(r0.w * s);
  a[4] = (short)f2bf(r1.x * s); a[5] = (short)f2bf(r1.y * s);
  a[6] = (short)f2bf(r1.z * s); a[7] = (short)f2bf(r1.w * s);
  return a;
}
// swizzled bf16 LDS helpers (XOR byte bits 4-6 with row&7); rowB multiple of 128
__device__ __forceinline__ void stb(char* base, int row, int rowB, int colByte, u16 v) {
  *(u16*)(base + row * rowB + (colByte ^ ((row & 7) << 4))) = v;
}
__device__ __forceinline__ u16 ldbs(const char* base, int row, int rowB, int colByte) {
  return *(const u16*)(base + row * rowB + (colByte ^ ((row & 7) << 4)));
}
__device__ __forceinline__ bf16x8 ldb8(const char* base, int row, int rowB, int colByte) {
  return *(const bf16x8*)(base + row * rowB + (colByte ^ ((row & 7) << 4)));
}
__device__ __forceinline__ void stb16(char* base, int row, int rowB, int colByte, bf16x8 v) {
  *(bf16x8*)(base + row * rowB + (colByte ^ ((row & 7) << 4))) = v;
}
// scale elements by sh1[(m0+j)%3]
__device__ __forceinline__ bf16x8 scale8_sh1(bf16x8 v, int m0, float t0, float t1, float t2) {
  float x0 = (m0 == 0) ? t0 : ((m0 == 1) ? t1 : t2);
  float x1 = (m0 == 0) ? t1 : ((m0 == 1) ? t2 : t0);
  float x2 = (m0 == 0) ? t2 : ((m0 == 1) ? t0 : t1);
  bf16x8 r;
  r[0] = (short)f2bf(bf2f((u16)v[0]) * x0); r[1] = (short)f2bf(bf2f((u16)v[1]) * x1);
  r[2] = (short)f2bf(bf2f((u16)v[2]) * x2); r[3] = (short)f2bf(bf2f((u16)v[3]) * x0);
  r[4] = (short)f2bf(bf2f((u16)v[4]) * x1); r[5] = (short)f2bf(bf2f((u16)v[5]) * x2);
  r[6] = (short)f2bf(bf2f((u16)v[6]) * x0); r[7] = (short)f2bf(bf2f((u16)v[7]) * x1);
  return r;
}

// ---------------- weight arena (element offsets) ----------------
#define OW_W2S   0        /* [128 u][2048 k=s*128+v]  (sc_s, SC_S_SCALE folded) */
#define OW_BTV   262144   /* [64 u][1024 k=s*64+v]    (sc_v, SC_V_SCALE folded) */
// fragment-linear: elem = (nt*(K/32)+kc)*512 + lane*8 + j
#define OW_PRE0  327680   /* N=128 K=128 */
#define OW_PRE1X 344064   /* N=192 K=192 block-diag */
#define OW_SS    380928   /* N=192 K=384 */
#define OW_VSX   454656   /* N=192 K=576 replicated (sh1 via A) */
#define OW_SV    565248   /* N=64  K=384 */
#define OW_VVX   589824   /* N=192 K=576 block-diag */
#define OW_F1    700416   /* N=64  K=128 */
#define OW_F2    708608   /* N=64  K=64  */
#define OW_F3    712704   /* N=192 K=64  */
#define OW_P0    724992   /* N=128 K=128 */
#define OW_P1X   741376   /* N=192 K=192 block-diag */
#define OW_END   778240

// ---------------- K0: weight prep ----------------
__device__ __forceinline__ void frag_uc(int oo, int K, int& up, int& c) {
  int per = (K >> 5) << 9;
  int nt = oo / per, r = oo % per;
  int kc = r >> 9, r2 = r & 511;
  int ln = r2 >> 3, j = r2 & 7;
  up = nt * 16 + (ln & 15);
  c = kc * 32 + (ln >> 4) * 8 + j;
}

__global__ __launch_bounds__(256) void k_prep(
    const float* __restrict__ Wsc_s, const float* __restrict__ Wsc_v,
    const float* __restrict__ Wpre0, const float* __restrict__ Wpre1,
    const float* __restrict__ Wss, const float* __restrict__ Wvs,
    const float* __restrict__ Wsv, const float* __restrict__ Wvv,
    const float* __restrict__ Wf1, const float* __restrict__ Wf2,
    const float* __restrict__ Wf3, const float* __restrict__ Wpost0,
    const float* __restrict__ Wpost1, u16* __restrict__ dst) {
  int o = blockIdx.x * 256 + threadIdx.x;
  if (o >= OW_END) return;
  float v;
  int up, c;
  if (o < OW_BTV) {
    int u = o >> 11, k = o & 2047, s = k >> 7, vv = k & 127;
    v = Wsc_s[((size_t)(vv * 16 + s)) * 128 + u] * SC_S_SCALE;
  } else if (o < OW_PRE0) {
    int oo = o - OW_BTV; int u = oo >> 10, k = oo & 1023, s = k >> 6, vv = k & 63;
    v = Wsc_v[((size_t)(vv * 16 + s)) * 64 + u] * SC_V_SCALE;
  } else if (o < OW_PRE1X) {
    frag_uc(o - OW_PRE0, 128, up, c);
    v = Wpre0[c * 128 + up] * INV_SQRT128;
  } else if (o < OW_SS) {
    frag_uc(o - OW_PRE1X, 192, up, c);
    int u = up / 3, m = up % 3, vv = c / 3, mp = c % 3;
    v = (m == mp) ? Wpre1[vv * 64 + u] * INV_8 : 0.f;
  } else if (o < OW_VSX) {
    frag_uc(o - OW_SS, 384, up, c);
    v = Wss[c * 192 + up] * (INV_S384 * RSQRT2);
  } else if (o < OW_SV) {
    frag_uc(o - OW_VSX, 576, up, c);
    int p = c / 192, r = c % 192, K = p * 64 + r / 3;
    v = Wvs[K * 192 + up] * (INV_24 * RSQRT2);
  } else if (o < OW_VVX) {
    frag_uc(o - OW_SV, 384, up, c);
    v = Wsv[c * 64 + up] * (INV_S384 * RSQRT2);
  } else if (o < OW_F1) {
    frag_uc(o - OW_VVX, 576, up, c);
    int u = up / 3, m = up % 3, p = c / 192, r = c % 192, vv = r / 3, mp = r % 3;
    v = (m == mp) ? Wvv[(p * 64 + vv) * 64 + u] * (INV_S192 * RSQRT2) : 0.f;
  } else if (o < OW_F2) {
    frag_uc(o - OW_F1, 128, up, c);
    v = Wf1[c * 64 + up];
  } else if (o < OW_F3) {
    frag_uc(o - OW_F2, 64, up, c);
    v = Wf2[c * 64 + up];
  } else if (o < OW_P0) {
    frag_uc(o - OW_F3, 64, up, c);
    v = Wf3[c * 192 + up];
  } else if (o < OW_P1X) {
    frag_uc(o - OW_P0, 128, up, c);
    v = Wpost0[c * 128 + up] * INV_SQRT128;
  } else {
    frag_uc(o - OW_P1X, 192, up, c);
    int u = up / 3, m = up % 3, vv = c / 3, mp = c % 3;
    v = (m == mp) ? Wpost1[vv * 64 + u] * INV_8 : 0.f;
  }
  dst[o] = f2bf(v);
}

// ---------------- K1: merged sc (temp-acc + oh scale on accumulator) ----------------
#define MEs 64
__global__ __launch_bounds__(256, 2) void k_sc(
    const float* __restrict__ edge_fea, const float* __restrict__ ohp,
    const u16* __restrict__ W2s, const u16* __restrict__ Btv,
    float* __restrict__ out) {
  __shared__ char esB[16384];   // [64][256B] swizzled
  __shared__ char evT[24576];   // [192 r=3e+m][128B] swizzled, col=v
  __shared__ float ohL[64][16];
  __shared__ char Bbuf[32768];  // s-phase [128][256B]; v-phase reuse [64][128B]
  const int t = threadIdx.x, lane = t & 63, ww = t >> 6;
  const int l15 = lane & 15, q8 = lane >> 4, q4 = q8 << 2, cbl = q8 << 4;
  const int e0 = blockIdx.x * MEs;
  const int nE = min(MEs, E_TOT - e0);

  // stage es/ev once
  for (int o = t; o < 2560; o += 256) {
    int c = o % 40, e = o / 40;
    float4 r0 = make_float4(0.f, 0.f, 0.f, 0.f), r1 = r0;
    if (e < nE) {
      const float* src = edge_fea + (size_t)(e0 + e) * 320 + c * 8;
      r0 = *(const float4*)src; r1 = *(const float4*)(src + 4);
    }
    if (c < 16) stb16(esB, e, 256, c * 16, pack8(r0, r1, 1.f));
    else {
      int base = (c - 16) * 8;
      float vals[8] = {r0.x, r0.y, r0.z, r0.w, r1.x, r1.y, r1.z, r1.w};
      #pragma unroll
      for (int z = 0; z < 8; ++z) {
        int cc = base + z;
        stb(evT, 3 * e + cc % 3, 128, (cc / 3) * 2, f2bf(vals[z]));
      }
    }
  }
  for (int o = t; o < 1024; o += 256) {
    int e = o >> 4, s = o & 15;
    ohL[e][s] = (e < nE) ? ohp[(size_t)(e0 + e) * 16 + s] : 0.f;
  }
  __syncthreads();

  // ---- sc_s: acc[e][u] = sum_s oh[e,s] * (es @ W_s) ----
  {
    bf16x8 afh[4][4];
    #pragma unroll
    for (int rt = 0; rt < 4; ++rt)
      #pragma unroll
      for (int ks = 0; ks < 4; ++ks)
        afh[rt][ks] = ldb8(esB, rt * 16 + l15, 256, ks * 64 + cbl);
    f32x4 acc[8];
    #pragma unroll
    for (int i = 0; i < 8; ++i) acc[i] = F4Z;
    for (int s = 0; s < 16; ++s) {
      const char* sb = (const char*)W2s + s * 256;
      #pragma unroll
      for (int it = 0; it < 8; ++it) {
        int n = it * 256 + t;
        int u = n >> 4, gp = n & 15, g = gp ^ (u & 7);
        gl_lds16(sb + (size_t)u * 4096 + g * 16, Bbuf + n * 16);
      }
      __syncthreads();
      f32x4 tmp[8];
      #pragma unroll
      for (int i = 0; i < 8; ++i) tmp[i] = F4Z;
      #pragma unroll
      for (int ks = 0; ks < 4; ++ks) {
        bf16x8 b0 = ldb8(Bbuf, ww * 32 + l15, 256, ks * 64 + cbl);
        bf16x8 b1 = ldb8(Bbuf, ww * 32 + 16 + l15, 256, ks * 64 + cbl);
        #pragma unroll
        for (int rt = 0; rt < 4; ++rt) {
          tmp[rt * 2 + 0] = MFMA(afh[rt][ks], b0, tmp[rt * 2 + 0], 0, 0, 0);
          tmp[rt * 2 + 1] = MFMA(afh[rt][ks], b1, tmp[rt * 2 + 1], 0, 0, 0);
        }
      }
      #pragma unroll
      for (int rt = 0; rt < 4; ++rt)
        #pragma unroll
        for (int j = 0; j < 4; ++j) {
          float oh = ohL[rt * 16 + q4 + j][s];
          acc[rt * 2 + 0][j] += oh * tmp[rt * 2 + 0][j];
          acc[rt * 2 + 1][j] += oh * tmp[rt * 2 + 1][j];
        }
      __syncthreads();
    }
    #pragma unroll
    for (int rt = 0; rt < 4; ++rt)
      #pragma unroll
      for (int ct = 0; ct < 2; ++ct) {
        int u = ww * 32 + ct * 16 + l15;
        #pragma unroll
        for (int j = 0; j < 4; ++j) {
          int e = rt * 16 + q4 + j;
          if (e < nE) out[(size_t)(e0 + e) * DIM + u] = acc[rt * 2 + ct][j];
        }
      }
  }

  // ---- sc_v: rows r=3e+m, acc += oh * (evT @ Wv_s) ----
  {
    f32x4 acc[12];
    #pragma unroll
    for (int i = 0; i < 12; ++i) acc[i] = F4Z;
    for (int s = 0; s < 16; ++s) {
      #pragma unroll
      for (int it = 0; it < 2; ++it) {
        int n = it * 256 + t;
        int u = n >> 3, gp = n & 7, g = gp ^ (u & 7);
        gl_lds16((const char*)Btv + (size_t)u * 2048 + s * 128 + g * 16, Bbuf + n * 16);
      }
      __syncthreads();
      f32x4 tmp[12];
      #pragma unroll
      for (int i = 0; i < 12; ++i) tmp[i] = F4Z;
      #pragma unroll
      for (int ks = 0; ks < 2; ++ks) {
        bf16x8 b = ldb8(Bbuf, ww * 16 + l15, 128, ks * 64 + cbl);
        #pragma unroll
        for (int rt = 0; rt < 12; ++rt) {
          bf16x8 a = ldb8(evT, rt * 16 + l15, 128, ks * 64 + cbl);
          tmp[rt] = MFMA(a, b, tmp[rt], 0, 0, 0);
        }
      }
      #pragma unroll
      for (int rt = 0; rt < 12; ++rt)
        #pragma unroll
        for (int j = 0; j < 4; ++j) {
          int r = rt * 16 + q4 + j;
          acc[rt][j] += ohL[r / 3][s] * tmp[rt][j];
        }
      __syncthreads();
    }
    int u = ww * 16 + l15;
    #pragma unroll
    for (int rt = 0; rt < 12; ++rt)
      #pragma unroll
      for (int j = 0; j < 4; ++j) {
        int r = rt * 16 + q4 + j, e = r / 3, m = r - e * 3;
        if (e < nE) out[(size_t)(e0 + e) * DIM + 128 + u * 3 + m] = acc[rt][j];
      }
  }
}

// ---------------- K2: fused chain, M=32, 512 thr, 2 blocks/CU (verified R6) ----------------
#define A_SZ 78592
__global__ __launch_bounds__(512, 4) void k_chain(
    const float* __restrict__ node_fea, const float* __restrict__ edge_sh,
    const float* __restrict__ edge_fea, const float* __restrict__ elen,
    const int* __restrict__ eidx, const u16* __restrict__ wbf,
    const float* __restrict__ bpre0, const float* __restrict__ bf1,
    const float* __restrict__ bf2, const float* __restrict__ bf3,
    const float* __restrict__ bpost0, float* __restrict__ out) {
  __shared__ char AR[A_SZ];
  float* shF = (float*)(AR + 77824);  // [32][4]
  int* ijL = (int*)(AR + 78336);      // [2][32]
  const int t = threadIdx.x, lane = t & 63, wv = t >> 6;
  const int l15 = lane & 15, q8 = lane >> 4, q4 = q8 << 2, cbl = q8 << 4;
  const int e0 = blockIdx.x * 32;

#define SA(b) (AR + (b) * 8192)
#define VA(b) (AR + 24576 + (b) * 12288)
  char* wB = AR;
  char* zsB = AR + 12288;
  char* gateB = AR + 20480;
  char* zvB = AR + 24576;
  char* t1B = AR + 61440;
  char* hB = AR + 65536;
  char* elB = AR + 69632;

  if (t < 64) { int p = t >> 5, e = t & 31; ijL[p * 32 + e] = eidx[p * E_TOT + e0 + e]; }
  if (t >= 64 && t < 192) { int o = t - 64; shF[o] = edge_sh[(size_t)e0 * 4 + o]; }
  __syncthreads();

  // ---- P0: staging (16B swizzled chunks) ----
  for (int o = t; o < 1280; o += 512) {
    int c = o % 40, e = o / 40;
    const float* src = edge_fea + (size_t)(e0 + e) * 320 + c * 8;
    float4 r0 = *(const float4*)src, r1 = *(const float4*)(src + 4);
    bf16x8 v = pack8(r0, r1, 1.f);
    if (c < 16) stb16(SA(2), e, 256, c * 16, v);
    else        stb16(VA(2), e, 384, (c - 16) * 16, v);
  }
  for (int o = t; o < 2560; o += 512) {
    int c = o % 40, tmp = o / 40, e = tmp & 31, p = tmp >> 5;
    const float* src = node_fea + (size_t)ijL[p * 32 + e] * 320 + c * 8;
    float4 r0 = *(const float4*)src, r1 = *(const float4*)(src + 4);
    bf16x8 v = pack8(r0, r1, 1.f);
    if (c < 16) stb16(SA(p), e, 256, c * 16, v);
    else        stb16(VA(p), e, 384, (c - 16) * 16, v);
  }
  for (int o = t; o < 512; o += 512) {
    int c = o & 15, e = o >> 4;
    const float* src = elen + (size_t)(e0 + e) * 128 + c * 8;
    float4 r0 = *(const float4*)src, r1 = *(const float4*)(src + 4);
    stb16(elB, e, 256, c * 16, pack8(r0, r1, 1.f));
  }
  __syncthreads();

  // ---- P1: v-pre (w0-3) | s-pre (w4-5) | h1 (w6-7) ----
  f32x4 acc[8];
  #pragma unroll
  for (int a = 0; a < 8; ++a) acc[a] = F4Z;
  if (wv < 4) {
    for (int kc = 0; kc < 6; ++kc) {
      bf16x8 a0 = ldb8(VA(2), l15, 384, kc * 64 + cbl);
      bf16x8 a1 = ldb8(VA(2), 16 + l15, 384, kc * 64 + cbl);
      #pragma unroll
      for (int i = 0; i < 3; ++i) {
        int nt = wv * 3 + i;
        bf16x8 b = *(const bf16x8*)(wbf + OW_PRE1X + (((size_t)nt * 6 + kc) << 9) + lane * 8);
        acc[i] = MFMA(a0, b, acc[i], 0, 0, 0);
        acc[3 + i] = MFMA(a1, b, acc[3 + i], 0, 0, 0);
      }
    }
  } else if (wv < 6) {
    for (int kc = 0; kc < 4; ++kc) {
      bf16x8 a0 = ldb8(SA(2), l15, 256, kc * 64 + cbl);
      bf16x8 a1 = ldb8(SA(2), 16 + l15, 256, kc * 64 + cbl);
      #pragma unroll
      for (int i = 0; i < 4; ++i) {
        int nt = (wv - 4) * 4 + i;
        bf16x8 b = *(const bf16x8*)(wbf + OW_PRE0 + (((size_t)nt * 4 + kc) << 9) + lane * 8);
        acc[i] = MFMA(a0, b, acc[i], 0, 0, 0);
        acc[4 + i] = MFMA(a1, b, acc[4 + i], 0, 0, 0);
      }
    }
  } else {
    for (int kc = 0; kc < 4; ++kc) {
      bf16x8 a0 = ldb8(elB, l15, 256, kc * 64 + cbl);
      bf16x8 a1 = ldb8(elB, 16 + l15, 256, kc * 64 + cbl);
      #pragma unroll
      for (int i = 0; i < 2; ++i) {
        int nt = (wv - 6) * 2 + i;
        bf16x8 b = *(const bf16x8*)(wbf + OW_F1 + (((size_t)nt * 4 + kc) << 9) + lane * 8);
        acc[i] = MFMA(a0, b, acc[i], 0, 0, 0);
        acc[2 + i] = MFMA(a1, b, acc[2 + i], 0, 0, 0);
      }
    }
  }
  __syncthreads();  // BAR1a
  if (wv < 4) {
    #pragma unroll
    for (int mt = 0; mt < 2; ++mt)
      #pragma unroll
      for (int i = 0; i < 3; ++i) {
        int up = (wv * 3 + i) * 16 + l15;
        #pragma unroll
        for (int j = 0; j < 4; ++j)
          stb(VA(2), mt * 16 + q4 + j, 384, up * 2, f2bf(acc[mt * 3 + i][j]));
      }
  } else if (wv < 6) {
    #pragma unroll
    for (int i = 0; i < 4; ++i) {
      int u = ((wv - 4) * 4 + i) * 16 + l15;
      float bias = bpre0[u];
      #pragma unroll
      for (int mt = 0; mt < 2; ++mt)
        #pragma unroll
        for (int j = 0; j < 4; ++j)
          stb(SA(2), mt * 16 + q4 + j, 256, u * 2, f2bf(acc[mt * 4 + i][j] + bias));
    }
  } else {
    #pragma unroll
    for (int i = 0; i < 2; ++i) {
      int u = ((wv - 6) * 2 + i) * 16 + l15;
      float bias = bf1[u];
      #pragma unroll
      for (int mt = 0; mt < 2; ++mt)
        #pragma unroll
        for (int j = 0; j < 4; ++j)
          stb(hB, mt * 16 + q4 + j, 128, u * 2, f2bf(siluf_(acc[mt * 2 + i][j] + bias)));
    }
  }
  __syncthreads();  // BAR1b

  // ---- P2: out_s (w0-5, acc4) | t1 (w6-7, acc4) ; h2 (all, acc1) ----
  f32x4 os[4] = {F4Z, F4Z, F4Z, F4Z};
  f32x4 h2a = F4Z;
  {
    const int hmt = wv >> 2, hnt = wv & 3;
    #pragma unroll
    for (int kc = 0; kc < 2; ++kc) {
      bf16x8 a = ldb8(hB, hmt * 16 + l15, 128, kc * 64 + cbl);
      bf16x8 b = *(const bf16x8*)(wbf + OW_F2 + (((size_t)hnt * 2 + kc) << 9) + lane * 8);
      h2a = MFMA(a, b, h2a, 0, 0, 0);
    }
  }
  if (wv < 6) {
    for (int kc = 0; kc < 12; ++kc) {
      int buf = kc >> 2, cB = (kc & 3) * 64 + cbl;
      bf16x8 a0 = ldb8(SA(buf), l15, 256, cB);
      bf16x8 a1 = ldb8(SA(buf), 16 + l15, 256, cB);
      #pragma unroll
      for (int i = 0; i < 2; ++i) {
        int nt = wv * 2 + i;
        bf16x8 b = *(const bf16x8*)(wbf + OW_SS + (((size_t)nt * 12 + kc) << 9) + lane * 8);
        os[i] = MFMA(a0, b, os[i], 0, 0, 0);
        os[2 + i] = MFMA(a1, b, os[2 + i], 0, 0, 0);
      }
    }
    #pragma unroll
    for (int mt = 0; mt < 2; ++mt)
      #pragma unroll
      for (int i = 0; i < 2; ++i)
        #pragma unroll
        for (int j = 0; j < 4; ++j)
          os[mt * 2 + i][j] *= shF[(mt * 16 + q4 + j) * 4 + 0];
    float sa0 = shF[l15 * 4 + 1], sa1 = shF[l15 * 4 + 2], sa2 = shF[l15 * 4 + 3];
    float sb0 = shF[(16 + l15) * 4 + 1], sb1 = shF[(16 + l15) * 4 + 2], sb2 = shF[(16 + l15) * 4 + 3];
    for (int p = 0; p < 3; ++p)
      for (int kc6 = 0; kc6 < 6; ++kc6) {
        int cB = kc6 * 64 + cbl;
        int m0 = (2 * (kc6 + q8)) % 3;
        bf16x8 a0 = scale8_sh1(ldb8(VA(p), l15, 384, cB), m0, sa0, sa1, sa2);
        bf16x8 a1 = scale8_sh1(ldb8(VA(p), 16 + l15, 384, cB), m0, sb0, sb1, sb2);
        int kcg = p * 6 + kc6;
        #pragma unroll
        for (int i = 0; i < 2; ++i) {
          int nt = wv * 2 + i;
          bf16x8 b = *(const bf16x8*)(wbf + OW_VSX + (((size_t)nt * 18 + kcg) << 9) + lane * 8);
          os[i] = MFMA(a0, b, os[i], 0, 0, 0);
          os[2 + i] = MFMA(a1, b, os[2 + i], 0, 0, 0);
        }
      }
  } else {
    for (int kc = 0; kc < 12; ++kc) {
      int buf = kc >> 2, cB = (kc & 3) * 64 + cbl;
      bf16x8 a0 = ldb8(SA(buf), l15, 256, cB);
      bf16x8 a1 = ldb8(SA(buf), 16 + l15, 256, cB);
      #pragma unroll
      for (int i = 0; i < 2; ++i) {
        int nt = (wv - 6) * 2 + i;
        bf16x8 b = *(const bf16x8*)(wbf + OW_SV + (((size_t)nt * 12 + kc) << 9) + lane * 8);
        os[i] = MFMA(a0, b, os[i], 0, 0, 0);
        os[2 + i] = MFMA(a1, b, os[2 + i], 0, 0, 0);
      }
    }
  }
  __syncthreads();  // BAR2a
  {
    const int hmt = wv >> 2;
    int u = (wv & 3) * 16 + l15;
    float bias = bf2[u];
    #pragma unroll
    for (int j = 0; j < 4; ++j)
      stb(hB, hmt * 16 + q4 + j, 128, u * 2, f2bf(siluf_(h2a[j] + bias)));
  }
  if (wv >= 6) {
    #pragma unroll
    for (int mt = 0; mt < 2; ++mt)
      #pragma unroll
      for (int i = 0; i < 2; ++i) {
        int u = ((wv - 6) * 2 + i) * 16 + l15;
        #pragma unroll
        for (int j = 0; j < 4; ++j)
          stb(t1B, mt * 16 + q4 + j, 128, u * 2, f2bf(os[mt * 2 + i][j]));
      }
  }
  __syncthreads();  // BAR2b

  // ---- P3: w = h2@Wf3 + bf3 ----
  {
    f32x4 wa[3] = {F4Z, F4Z, F4Z};
    const int mtw = wv >> 2;
    #pragma unroll
    for (int kc = 0; kc < 2; ++kc) {
      bf16x8 a = ldb8(hB, mtw * 16 + l15, 128, kc * 64 + cbl);
      #pragma unroll
      for (int i = 0; i < 3; ++i) {
        int nt = (wv & 3) * 3 + i;
        bf16x8 b = *(const bf16x8*)(wbf + OW_F3 + (((size_t)nt * 2 + kc) << 9) + lane * 8);
        wa[i] = MFMA(a, b, wa[i], 0, 0, 0);
      }
    }
    #pragma unroll
    for (int i = 0; i < 3; ++i) {
      int up = ((wv & 3) * 3 + i) * 16 + l15;
      float bias = bf3[up];
      #pragma unroll
      for (int j = 0; j < 4; ++j)
        stb(wB, mtw * 16 + q4 + j, 384, up * 2, f2bf(wa[i][j] + bias));
    }
  }
  __syncthreads();  // BAR3

  // ---- P4: gating (w0-5) + out_v MFMAs (all) ----
  if (wv < 6) {
    #pragma unroll
    for (int mt = 0; mt < 2; ++mt)
      #pragma unroll
      for (int i = 0; i < 2; ++i) {
        int up = (wv * 2 + i) * 16 + l15;
        #pragma unroll
        for (int j = 0; j < 4; ++j) {
          int e = mt * 16 + q4 + j;
          float w_ = bf2f(ldbs(wB, e, 384, up * 2));
          float o_ = os[mt * 2 + i][j];
          if (up < 128) stb(zsB, e, 256, up * 2, f2bf(siluf_(o_) * w_));
          else stb(gateB, e, 128, (up - 128) * 2, f2bf(sigmoidf_(o_) * w_));
        }
      }
  }
  f32x4 ov[3] = {F4Z, F4Z, F4Z};
  {
    const int mtv = wv >> 2;
    for (int p = 0; p < 3; ++p)
      for (int kc6 = 0; kc6 < 6; ++kc6) {
        int cB = kc6 * 64 + cbl;
        bf16x8 a = ldb8(VA(p), mtv * 16 + l15, 384, cB);
        int kcg = p * 6 + kc6;
        #pragma unroll
        for (int i = 0; i < 3; ++i) {
          int nt = (wv & 3) * 3 + i;
          bf16x8 b = *(const bf16x8*)(wbf + OW_VVX + (((size_t)nt * 18 + kcg) << 9) + lane * 8);
          ov[i] = MFMA(a, b, ov[i], 0, 0, 0);
        }
      }
  }
  __syncthreads();  // BAR4
  {
    const int mtv = wv >> 2;
    #pragma unroll
    for (int i = 0; i < 3; ++i) {
      int up = ((wv & 3) * 3 + i) * 16 + l15;
      int u = (up * 683) >> 11, m = up - 3 * u;
      #pragma unroll
      for (int j = 0; j < 4; ++j) {
        int e = mtv * 16 + q4 + j;
        float t1v = bf2f(ldbs(t1B, e, 128, u * 2));
        float g = bf2f(ldbs(gateB, e, 128, u * 2));
        float val = ov[i][j] * shF[e * 4 + 0] + t1v * shF[e * 4 + 1 + m];
        stb(zvB, e, 384, up * 2, f2bf(val * g));
      }
    }
  }
  __syncthreads();  // BAR5

  // ---- P5: post0 + post1, RMW onto sc in d_out ----
  {
    f32x4 p0[2] = {F4Z, F4Z};
    #pragma unroll
    for (int kc = 0; kc < 4; ++kc) {
      int cB = kc * 64 + cbl;
      bf16x8 a0 = ldb8(zsB, l15, 256, cB);
      bf16x8 a1 = ldb8(zsB, 16 + l15, 256, cB);
      bf16x8 b = *(const bf16x8*)(wbf + OW_P0 + (((size_t)wv * 4 + kc) << 9) + lane * 8);
      p0[0] = MFMA(a0, b, p0[0], 0, 0, 0);
      p0[1] = MFMA(a1, b, p0[1], 0, 0, 0);
    }
    int u = wv * 16 + l15;
    float bias = bpost0[u];
    #pragma unroll
    for (int mt = 0; mt < 2; ++mt)
      #pragma unroll
      for (int j = 0; j < 4; ++j) {
        size_t o = (size_t)(e0 + mt * 16 + q4 + j) * DIM + u;
        out[o] = out[o] + p0[mt][j] + bias;
      }
  }
  {
    f32x4 p1[3] = {F4Z, F4Z, F4Z};
    const int mtv = wv >> 2;
    #pragma unroll
    for (int kc = 0; kc < 6; ++kc) {
      int cB = kc * 64 + cbl;
      bf16x8 a = ldb8(zvB, mtv * 16 + l15, 384, cB);
      #pragma unroll
      for (int i = 0; i < 3; ++i) {
        int nt = (wv & 3) * 3 + i;
        bf16x8 b = *(const bf16x8*)(wbf + OW_P1X + (((size_t)nt * 6 + kc) << 9) + lane * 8);
        p1[i] = MFMA(a, b, p1[i], 0, 0, 0);
      }
    }
    #pragma unroll
    for (int i = 0; i < 3; ++i) {
      int up = ((wv & 3) * 3 + i) * 16 + l15;
      #pragma unroll
      for (int j = 0; j < 4; ++j) {
        size_t o = (size_t)(e0 + mtv * 16 + q4 + j) * DIM + 128 + up;
        out[o] = out[o] + p1[i][j];
      }
    }
  }
#undef SA
#undef VA
}

// ---------------- K3: group statistics (float4) ----------------
__global__ __launch_bounds__(256) void k_stats(
    const float* __restrict__ out, const int* __restrict__ eidx,
    const int* __restrict__ batch, float* __restrict__ stats) {
  __shared__ float gacc[16][4];
  const int t = threadIdx.x;
  if (t < 64) ((float*)gacc)[t] = 0.0f;
  __syncthreads();
  const int el = t >> 4, l = t & 15;
  for (int ebase = blockIdx.x * 16; ebase < E_TOT; ebase += gridDim.x * 16) {
    int e = ebase + el;
    const float4* z4 = (const float4*)(out + (size_t)e * DIM);
    float s1 = 0, s2 = 0, s2v = 0;
    float4 a = z4[l], b = z4[16 + l];
    s1 = a.x + a.y + a.z + a.w + b.x + b.y + b.z + b.w;
    s2 = a.x * a.x + a.y * a.y + a.z * a.z + a.w * a.w +
         b.x * b.x + b.y * b.y + b.z * b.z + b.w * b.w;
    #pragma unroll
    for (int p = 0; p < 3; ++p) {
      float4 c = z4[32 + p * 16 + l];
      s2v += c.x * c.x + c.y * c.y + c.z * c.z + c.w * c.w;
    }
    #pragma unroll
    for (int msk = 8; msk; msk >>= 1) {
      s1 += __shfl_xor(s1, msk);
      s2 += __shfl_xor(s2, msk);
      s2v += __shfl_xor(s2v, msk);
    }
    if (l == 0) {
      int g = batch[eidx[e]];
      atomicAdd(&gacc[g][0], 1.0f);
      atomicAdd(&gacc[g][1], s1);
      atomicAdd(&gacc[g][2], s2);
      atomicAdd(&gacc[g][3], s2v);
    }
  }
  __syncthreads();
  if (t < 64) {
    float v = gacc[t >> 2][t & 3];
    if (v != 0.0f) atomicAdd(&stats[(t >> 2) * 16 + (t & 3)], v);
  }
}

// ---------------- K4: normalize + residual (float4) ----------------
__global__ __launch_bounds__(256) void k_norm(
    const float* __restrict__ edge_fea, const int* __restrict__ eidx,
    const int* __restrict__ batch, const float* __restrict__ stats,
    const float* __restrict__ gamma_s, const float* __restrict__ beta_s,
    const float* __restrict__ gamma_v, float* __restrict__ out) {
  __shared__ float meanL[16], invsL[16], invvL[16];
  __shared__ int gL[16];
  const int t = threadIdx.x;
  const int e0 = blockIdx.x * 16;
  if (t < 16) {
    float cnt = fmaxf(stats[t * 16 + 0], 1.0f);
    float m = stats[t * 16 + 1] / (cnt * 128.0f);
    float var = stats[t * 16 + 2] / (cnt * 128.0f) - m * m;
    meanL[t] = m;
    invsL[t] = rsqrtf(var + 1e-5f);
    invvL[t] = rsqrtf(stats[t * 16 + 3] / (cnt * 192.0f) + 1e-5f);
  }
  if (t >= 32 && t < 48) gL[t - 32] = batch[eidx[e0 + t - 32]];
  __syncthreads();
  for (int o = t; o < 16 * 80; o += 256) {
    int e = o / 80, q = o % 80;
    size_t idx = (size_t)(e0 + e) * 80 + q;
    float4 z = ((const float4*)out)[idx];
    float4 ef = ((const float4*)edge_fea)[idx];
    int g = gL[e];
    float4 r;
    if (q < 32) {
      int c = q * 4;
      r.x = (z.x - meanL[g]) * invsL[g] * gamma_s[c + 0] + beta_s[c + 0] + ef.x;
      r.y = (z.y - meanL[g]) * invsL[g] * gamma_s[c + 1] + beta_s[c + 1] + ef.y;
      r.z = (z.z - meanL[g]) * invsL[g] * gamma_s[c + 2] + beta_s[c + 2] + ef.z;
      r.w = (z.w - meanL[g]) * invsL[g] * gamma_s[c + 3] + beta_s[c + 3] + ef.w;
    } else {
      int cc = q * 4 - 128;
      r.x = z.x * invvL[g] * gamma_v[(cc + 0) / 3] + ef.x;
      r.y = z.y * invvL[g] * gamma_v[(cc + 1) / 3] + ef.y;
      r.z = z.z * invvL[g] * gamma_v[(cc + 2) / 3] + ef.z;
      r.w = z.w * invvL[g] * gamma_v[(cc + 3) / 3] + ef.w;
    }
    ((float4*)out)[idx] = r;
  }
}

extern "C" void kernel_launch(void* const* d_in, const int* in_sizes, int n_in,
                              void* d_out, int out_size, void* d_ws, size_t ws_size,
                              hipStream_t stream) {
  const float* node_fea = (const float*)d_in[0];
  const float* edge_oh  = (const float*)d_in[1];
  const float* edge_sh  = (const float*)d_in[2];
  const float* edge_fea = (const float*)d_in[3];
  const float* elen     = (const float*)d_in[4];
  const int*   eidx     = (const int*)d_in[5];
  const int*   batch    = (const int*)d_in[6];
  const float* Wsc_s    = (const float*)d_in[7];
  const float* Wsc_v    = (const float*)d_in[8];
  const float* Wpre0    = (const float*)d_in[9];
  const float* bpre0    = (const float*)d_in[10];
  const float* Wpre1    = (const float*)d_in[11];
  const float* Wss      = (const float*)d_in[12];
  const float* Wvs      = (const float*)d_in[13];
  const float* Wsv      = (const float*)d_in[14];
  const float* Wvv      = (const float*)d_in[15];
  const float* Wf1      = (const float*)d_in[16];
  const float* bf1      = (const float*)d_in[17];
  const float* Wf2      = (const float*)d_in[18];
  const float* bf2      = (const float*)d_in[19];
  const float* Wf3      = (const float*)d_in[20];
  const float* bf3      = (const float*)d_in[21];
  const float* Wpost0   = (const float*)d_in[22];
  const float* bpost0   = (const float*)d_in[23];
  const float* Wpost1   = (const float*)d_in[24];
  const float* gamma_s  = (const float*)d_in[25];
  const float* beta_s   = (const float*)d_in[26];
  const float* gamma_v  = (const float*)d_in[27];
  float* out = (float*)d_out;

  char* ws = (char*)d_ws;
  float* stats = (float*)ws;
  u16* wbf = (u16*)(ws + 1024);

  hipMemsetAsync(stats, 0, 16 * 16 * sizeof(float), stream);
  k_prep<<<(OW_END + 255) / 256, 256, 0, stream>>>(
      Wsc_s, Wsc_v, Wpre0, Wpre1, Wss, Wvs, Wsv, Wvv,
      Wf1, Wf2, Wf3, Wpost0, Wpost1, wbf);
  const int nblk64 = (E_TOT + MEs - 1) / MEs;  // 1563
  k_sc<<<nblk64, 256, 0, stream>>>(edge_fea, edge_oh, wbf + OW_W2S, wbf + OW_BTV, out);
  k_chain<<<E_TOT / 32, 512, 0, stream>>>(node_fea, edge_sh, edge_fea, elen, eidx,
                                          wbf, bpre0, bf1, bf2, bf3, bpost0, out);
  k_stats<<<512, 256, 0, stream>>>(out, eidx, batch, stats);
  k_norm<<<E_TOT / 16, 256, 0, stream>>>(edge_fea, eidx, batch, stats,
                                         gamma_s, beta_s, gamma_v, out);
}

// Round 9
// 652.707 us; speedup vs baseline: 3.7844x; 1.0100x over previous
//
#include <hip/hip_runtime.h>
#include <math.h>

typedef unsigned int u32;
typedef unsigned short u16;
typedef __attribute__((ext_vector_type(8))) short bf16x8;
typedef __attribute__((ext_vector_type(4))) float f32x4;

#define E_TOT 100000
constexpr int NS = 128, DIM = 320;

constexpr float SC_S_SCALE = 0.022097086912079608f;  // 1/sqrt(128*16)
constexpr float SC_V_SCALE = 0.03125f;               // 1/32
constexpr float INV_SQRT128 = 0.08838834764831845f;
constexpr float INV_8 = 0.125f;
constexpr float INV_S384 = 0.05103103630798288f;
constexpr float INV_24 = 0.041666666666666664f;
constexpr float INV_S192 = 0.07216878364870323f;
constexpr float RSQRT2 = 0.7071067811865476f;

#define MFMA __builtin_amdgcn_mfma_f32_16x16x32_bf16
#define F4Z (f32x4){0.f, 0.f, 0.f, 0.f}

__device__ __forceinline__ float sigmoidf_(float x) { return 1.0f / (1.0f + __expf(-x)); }
__device__ __forceinline__ float siluf_(float x) { return x * sigmoidf_(x); }
__device__ __forceinline__ float bf2f(u16 h) {
  u32 u = ((u32)h) << 16;
  return __builtin_bit_cast(float, u);
}
__device__ __forceinline__ u16 f2bf(float f) {
  u32 u = __builtin_bit_cast(u32, f);
  return (u16)((u + 0x7fffu + ((u >> 16) & 1u)) >> 16);
}
__device__ __forceinline__ void gl_lds16(const void* g, void* l) {
  __builtin_amdgcn_global_load_lds((const __attribute__((address_space(1))) u32*)g,
                                   (__attribute__((address_space(3))) u32*)l, 16, 0, 0);
}
__device__ __forceinline__ bf16x8 pack8(float4 r0, float4 r1, float s) {
  bf16x8 a;
  a[0] = (short)f2bf(r0.x * s); a[1] = (short)f2bf(r0.y * s);
  a[2] = (short)f2bf(r0.z * s); a[3] = (short)f2bf(r0.w * s);
  a[4] = (short)f2bf(r1.x * s); a[5] = (short)f2bf(r1.y * s);
  a[6] = (short)f2bf(r1.z * s); a[7] = (short)f2bf(r1.w * s);
  return a;
}
// swizzled bf16 LDS helpers (XOR byte bits 4-6 with row&7); rowB multiple of 128
__device__ __forceinline__ void stb(char* base, int row, int rowB, int colByte, u16 v) {
  *(u16*)(base + row * rowB + (colByte ^ ((row & 7) << 4))) = v;
}
__device__ __forceinline__ u16 ldbs(const char* base, int row, int rowB, int colByte) {
  return *(const u16*)(base + row * rowB + (colByte ^ ((row & 7) << 4)));
}
__device__ __forceinline__ bf16x8 ldb8(const char* base, int row, int rowB, int colByte) {
  return *(const bf16x8*)(base + row * rowB + (colByte ^ ((row & 7) << 4)));
}
__device__ __forceinline__ void stb16(char* base, int row, int rowB, int colByte, bf16x8 v) {
  *(bf16x8*)(base + row * rowB + (colByte ^ ((row & 7) << 4))) = v;
}

// ---------------- weight arena (element offsets) ----------------
#define OW_W2S   0        /* [128 u][2048 k=s*128+v]  (sc_s, SC_S_SCALE folded) */
#define OW_BTV   262144   /* [64 u][1024 k=s*64+v]    (sc_v, SC_V_SCALE folded) */
// fragment-linear: elem = (nt*(K/32)+kc)*512 + lane*8 + j
#define OW_PRE0  327680   /* N=128 K=128 */
#define OW_PRE1X 344064   /* N=192 K=192 block-diag */
#define OW_SS    380928   /* N=192 K=384 */
#define OW_VS    454656   /* N=192 K=192 (svh path) */
#define OW_SV    491520   /* N=64  K=384 */
#define OW_VVX   516096   /* N=192 K=576 block-diag */
#define OW_F1    626688   /* N=64  K=128 */
#define OW_F2    634880   /* N=64  K=64  */
#define OW_F3    638976   /* N=192 K=64  */
#define OW_P0    651264   /* N=128 K=128 */
#define OW_P1X   667648   /* N=192 K=192 block-diag */
#define OW_END   704512

// ---------------- K0: weight prep ----------------
__device__ __forceinline__ void frag_uc(int oo, int K, int& up, int& c) {
  int per = (K >> 5) << 9;
  int nt = oo / per, r = oo % per;
  int kc = r >> 9, r2 = r & 511;
  int ln = r2 >> 3, j = r2 & 7;
  up = nt * 16 + (ln & 15);
  c = kc * 32 + (ln >> 4) * 8 + j;
}

__global__ __launch_bounds__(256) void k_prep(
    const float* __restrict__ Wsc_s, const float* __restrict__ Wsc_v,
    const float* __restrict__ Wpre0, const float* __restrict__ Wpre1,
    const float* __restrict__ Wss, const float* __restrict__ Wvs,
    const float* __restrict__ Wsv, const float* __restrict__ Wvv,
    const float* __restrict__ Wf1, const float* __restrict__ Wf2,
    const float* __restrict__ Wf3, const float* __restrict__ Wpost0,
    const float* __restrict__ Wpost1, u16* __restrict__ dst) {
  int o = blockIdx.x * 256 + threadIdx.x;
  if (o >= OW_END) return;
  float v;
  int up, c;
  if (o < OW_BTV) {
    int u = o >> 11, k = o & 2047, s = k >> 7, vv = k & 127;
    v = Wsc_s[((size_t)(vv * 16 + s)) * 128 + u] * SC_S_SCALE;
  } else if (o < OW_PRE0) {
    int oo = o - OW_BTV; int u = oo >> 10, k = oo & 1023, s = k >> 6, vv = k & 63;
    v = Wsc_v[((size_t)(vv * 16 + s)) * 64 + u] * SC_V_SCALE;
  } else if (o < OW_PRE1X) {
    frag_uc(o - OW_PRE0, 128, up, c);
    v = Wpre0[c * 128 + up] * INV_SQRT128;
  } else if (o < OW_SS) {
    frag_uc(o - OW_PRE1X, 192, up, c);
    int u = up / 3, m = up % 3, vv = c / 3, mp = c % 3;
    v = (m == mp) ? Wpre1[vv * 64 + u] * INV_8 : 0.f;
  } else if (o < OW_VS) {
    frag_uc(o - OW_SS, 384, up, c);
    v = Wss[c * 192 + up] * (INV_S384 * RSQRT2);
  } else if (o < OW_SV) {
    frag_uc(o - OW_VS, 192, up, c);
    v = Wvs[c * 192 + up] * (INV_24 * RSQRT2);
  } else if (o < OW_VVX) {
    frag_uc(o - OW_SV, 384, up, c);
    v = Wsv[c * 64 + up] * (INV_S384 * RSQRT2);
  } else if (o < OW_F1) {
    frag_uc(o - OW_VVX, 576, up, c);
    int u = up / 3, m = up % 3, p = c / 192, r = c % 192, vv = r / 3, mp = r % 3;
    v = (m == mp) ? Wvv[(p * 64 + vv) * 64 + u] * (INV_S192 * RSQRT2) : 0.f;
  } else if (o < OW_F2) {
    frag_uc(o - OW_F1, 128, up, c);
    v = Wf1[c * 64 + up];
  } else if (o < OW_F3) {
    frag_uc(o - OW_F2, 64, up, c);
    v = Wf2[c * 64 + up];
  } else if (o < OW_P0) {
    frag_uc(o - OW_F3, 64, up, c);
    v = Wf3[c * 192 + up];
  } else if (o < OW_P1X) {
    frag_uc(o - OW_P0, 128, up, c);
    v = Wpost0[c * 128 + up] * INV_SQRT128;
  } else {
    frag_uc(o - OW_P1X, 192, up, c);
    int u = up / 3, m = up % 3, vv = c / 3, mp = c % 3;
    v = (m == mp) ? Wpost1[vv * 64 + u] * INV_8 : 0.f;
  }
  dst[o] = f2bf(v);
}

// ---------------- K1: merged sc (verified R7) ----------------
#define MEs 64
__global__ __launch_bounds__(256, 2) void k_sc(
    const float* __restrict__ edge_fea, const float* __restrict__ ohp,
    const u16* __restrict__ W2s, const u16* __restrict__ Btv,
    float* __restrict__ out) {
  __shared__ char esB[16384];   // [64][256B] swizzled
  __shared__ char evT[24576];   // [192 r=3e+m][128B] swizzled, col=v
  __shared__ float ohL[64][16];
  __shared__ char Bbuf[32768];
  const int t = threadIdx.x, lane = t & 63, ww = t >> 6;
  const int l15 = lane & 15, q8 = lane >> 4, q4 = q8 << 2, cbl = q8 << 4;
  const int e0 = blockIdx.x * MEs;
  const int nE = min(MEs, E_TOT - e0);

  for (int o = t; o < 2560; o += 256) {
    int c = o % 40, e = o / 40;
    float4 r0 = make_float4(0.f, 0.f, 0.f, 0.f), r1 = r0;
    if (e < nE) {
      const float* src = edge_fea + (size_t)(e0 + e) * 320 + c * 8;
      r0 = *(const float4*)src; r1 = *(const float4*)(src + 4);
    }
    if (c < 16) stb16(esB, e, 256, c * 16, pack8(r0, r1, 1.f));
    else {
      int base = (c - 16) * 8;
      float vals[8] = {r0.x, r0.y, r0.z, r0.w, r1.x, r1.y, r1.z, r1.w};
      #pragma unroll
      for (int z = 0; z < 8; ++z) {
        int cc = base + z;
        stb(evT, 3 * e + cc % 3, 128, (cc / 3) * 2, f2bf(vals[z]));
      }
    }
  }
  for (int o = t; o < 1024; o += 256) {
    int e = o >> 4, s = o & 15;
    ohL[e][s] = (e < nE) ? ohp[(size_t)(e0 + e) * 16 + s] : 0.f;
  }
  __syncthreads();

  {
    bf16x8 afh[4][4];
    #pragma unroll
    for (int rt = 0; rt < 4; ++rt)
      #pragma unroll
      for (int ks = 0; ks < 4; ++ks)
        afh[rt][ks] = ldb8(esB, rt * 16 + l15, 256, ks * 64 + cbl);
    f32x4 acc[8];
    #pragma unroll
    for (int i = 0; i < 8; ++i) acc[i] = F4Z;
    for (int s = 0; s < 16; ++s) {
      const char* sb = (const char*)W2s + s * 256;
      #pragma unroll
      for (int it = 0; it < 8; ++it) {
        int n = it * 256 + t;
        int u = n >> 4, gp = n & 15, g = gp ^ (u & 7);
        gl_lds16(sb + (size_t)u * 4096 + g * 16, Bbuf + n * 16);
      }
      __syncthreads();
      f32x4 tmp[8];
      #pragma unroll
      for (int i = 0; i < 8; ++i) tmp[i] = F4Z;
      #pragma unroll
      for (int ks = 0; ks < 4; ++ks) {
        bf16x8 b0 = ldb8(Bbuf, ww * 32 + l15, 256, ks * 64 + cbl);
        bf16x8 b1 = ldb8(Bbuf, ww * 32 + 16 + l15, 256, ks * 64 + cbl);
        #pragma unroll
        for (int rt = 0; rt < 4; ++rt) {
          tmp[rt * 2 + 0] = MFMA(afh[rt][ks], b0, tmp[rt * 2 + 0], 0, 0, 0);
          tmp[rt * 2 + 1] = MFMA(afh[rt][ks], b1, tmp[rt * 2 + 1], 0, 0, 0);
        }
      }
      #pragma unroll
      for (int rt = 0; rt < 4; ++rt)
        #pragma unroll
        for (int j = 0; j < 4; ++j) {
          float oh = ohL[rt * 16 + q4 + j][s];
          acc[rt * 2 + 0][j] += oh * tmp[rt * 2 + 0][j];
          acc[rt * 2 + 1][j] += oh * tmp[rt * 2 + 1][j];
        }
      __syncthreads();
    }
    #pragma unroll
    for (int rt = 0; rt < 4; ++rt)
      #pragma unroll
      for (int ct = 0; ct < 2; ++ct) {
        int u = ww * 32 + ct * 16 + l15;
        #pragma unroll
        for (int j = 0; j < 4; ++j) {
          int e = rt * 16 + q4 + j;
          if (e < nE) out[(size_t)(e0 + e) * DIM + u] = acc[rt * 2 + ct][j];
        }
      }
  }

  {
    f32x4 acc[12];
    #pragma unroll
    for (int i = 0; i < 12; ++i) acc[i] = F4Z;
    for (int s = 0; s < 16; ++s) {
      #pragma unroll
      for (int it = 0; it < 2; ++it) {
        int n = it * 256 + t;
        int u = n >> 3, gp = n & 7, g = gp ^ (u & 7);
        gl_lds16((const char*)Btv + (size_t)u * 2048 + s * 128 + g * 16, Bbuf + n * 16);
      }
      __syncthreads();
      f32x4 tmp[12];
      #pragma unroll
      for (int i = 0; i < 12; ++i) tmp[i] = F4Z;
      #pragma unroll
      for (int ks = 0; ks < 2; ++ks) {
        bf16x8 b = ldb8(Bbuf, ww * 16 + l15, 128, ks * 64 + cbl);
        #pragma unroll
        for (int rt = 0; rt < 12; ++rt) {
          bf16x8 a = ldb8(evT, rt * 16 + l15, 128, ks * 64 + cbl);
          tmp[rt] = MFMA(a, b, tmp[rt], 0, 0, 0);
        }
      }
      #pragma unroll
      for (int rt = 0; rt < 12; ++rt)
        #pragma unroll
        for (int j = 0; j < 4; ++j) {
          int r = rt * 16 + q4 + j;
          acc[rt][j] += ohL[r / 3][s] * tmp[rt][j];
        }
      __syncthreads();
    }
    int u = ww * 16 + l15;
    #pragma unroll
    for (int rt = 0; rt < 12; ++rt)
      #pragma unroll
      for (int j = 0; j < 4; ++j) {
        int r = rt * 16 + q4 + j, e = r / 3, m = r - e * 3;
        if (e < nE) out[(size_t)(e0 + e) * DIM + 128 + u * 3 + m] = acc[rt][j];
      }
  }
}

// ---------------- K2: fused chain + stats, M=32, 512 thr, 2 blocks/CU ----------------
// svh lives in elB (K 0..127, [32][256B]) + t1B (K 128..191, [32][128B]):
// elB dead after P1 (h1 done); t1B not written until after BAR2a. No SA aliasing.
#define A_SZ 78976
__global__ __launch_bounds__(512, 4) void k_chain(
    const float* __restrict__ node_fea, const float* __restrict__ edge_sh,
    const float* __restrict__ edge_fea, const float* __restrict__ elen,
    const int* __restrict__ eidx, const int* __restrict__ batch,
    const u16* __restrict__ wbf,
    const float* __restrict__ bpre0, const float* __restrict__ bf1,
    const float* __restrict__ bf2, const float* __restrict__ bf3,
    const float* __restrict__ bpost0, float* __restrict__ out,
    float* __restrict__ statsB) {
  __shared__ char AR[A_SZ];
  float* shF = (float*)(AR + 77824);  // [32][4]
  int* ijL = (int*)(AR + 78336);      // [2][32]
  float* sS  = (float*)(AR + 78592);  // [32] z-sum (s part)
  float* sS2 = (float*)(AR + 78720);  // [32] z2-sum (s part)
  float* sV  = (float*)(AR + 78848);  // [32] z2-sum (v part)
  const int t = threadIdx.x, lane = t & 63, wv = t >> 6;
  const int l15 = lane & 15, q8 = lane >> 4, q4 = q8 << 2, cbl = q8 << 4;
  const int e0 = blockIdx.x * 32;

#define SA(b) (AR + (b) * 8192)
#define VA(b) (AR + 24576 + (b) * 12288)
  char* wB = AR;
  char* zsB = AR + 12288;
  char* gateB = AR + 20480;
  char* zvB = AR + 24576;
  char* t1B = AR + 61440;   // svh K 128..191 during [BAR1c, BAR2a]; t1 after BAR2a
  char* hB = AR + 65536;
  char* elB = AR + 69632;   // elen during P1; svh K 0..127 after BAR1b

  if (t < 64) { int p = t >> 5, e = t & 31; ijL[p * 32 + e] = eidx[p * E_TOT + e0 + e]; }
  if (t >= 64 && t < 192) { int o = t - 64; shF[o] = edge_sh[(size_t)e0 * 4 + o]; }
  if (t >= 192 && t < 288) ((float*)(AR + 78592))[t - 192] = 0.f;
  __syncthreads();

  // ---- P0: staging ----
  for (int o = t; o < 1280; o += 512) {
    int c = o % 40, e = o / 40;
    const float* src = edge_fea + (size_t)(e0 + e) * 320 + c * 8;
    float4 r0 = *(const float4*)src, r1 = *(const float4*)(src + 4);
    bf16x8 v = pack8(r0, r1, 1.f);
    if (c < 16) stb16(SA(2), e, 256, c * 16, v);
    else        stb16(VA(2), e, 384, (c - 16) * 16, v);
  }
  for (int o = t; o < 2560; o += 512) {
    int c = o % 40, tmp = o / 40, e = tmp & 31, p = tmp >> 5;
    const float* src = node_fea + (size_t)ijL[p * 32 + e] * 320 + c * 8;
    float4 r0 = *(const float4*)src, r1 = *(const float4*)(src + 4);
    bf16x8 v = pack8(r0, r1, 1.f);
    if (c < 16) stb16(SA(p), e, 256, c * 16, v);
    else        stb16(VA(p), e, 384, (c - 16) * 16, v);
  }
  for (int o = t; o < 512; o += 512) {
    int c = o & 15, e = o >> 4;
    const float* src = elen + (size_t)(e0 + e) * 128 + c * 8;
    float4 r0 = *(const float4*)src, r1 = *(const float4*)(src + 4);
    stb16(elB, e, 256, c * 16, pack8(r0, r1, 1.f));
  }
  __syncthreads();

  // ---- P1: v-pre (w0-3) | s-pre (w4-5) | h1 (w6-7) ----
  f32x4 acc[8];
  #pragma unroll
  for (int a = 0; a < 8; ++a) acc[a] = F4Z;
  if (wv < 4) {
    for (int kc = 0; kc < 6; ++kc) {
      bf16x8 a0 = ldb8(VA(2), l15, 384, kc * 64 + cbl);
      bf16x8 a1 = ldb8(VA(2), 16 + l15, 384, kc * 64 + cbl);
      #pragma unroll
      for (int i = 0; i < 3; ++i) {
        int nt = wv * 3 + i;
        bf16x8 b = *(const bf16x8*)(wbf + OW_PRE1X + (((size_t)nt * 6 + kc) << 9) + lane * 8);
        acc[i] = MFMA(a0, b, acc[i], 0, 0, 0);
        acc[3 + i] = MFMA(a1, b, acc[3 + i], 0, 0, 0);
      }
    }
  } else if (wv < 6) {
    for (int kc = 0; kc < 4; ++kc) {
      bf16x8 a0 = ldb8(SA(2), l15, 256, kc * 64 + cbl);
      bf16x8 a1 = ldb8(SA(2), 16 + l15, 256, kc * 64 + cbl);
      #pragma unroll
      for (int i = 0; i < 4; ++i) {
        int nt = (wv - 4) * 4 + i;
        bf16x8 b = *(const bf16x8*)(wbf + OW_PRE0 + (((size_t)nt * 4 + kc) << 9) + lane * 8);
        acc[i] = MFMA(a0, b, acc[i], 0, 0, 0);
        acc[4 + i] = MFMA(a1, b, acc[4 + i], 0, 0, 0);
      }
    }
  } else {
    for (int kc = 0; kc < 4; ++kc) {
      bf16x8 a0 = ldb8(elB, l15, 256, kc * 64 + cbl);
      bf16x8 a1 = ldb8(elB, 16 + l15, 256, kc * 64 + cbl);
      #pragma unroll
      for (int i = 0; i < 2; ++i) {
        int nt = (wv - 6) * 2 + i;
        bf16x8 b = *(const bf16x8*)(wbf + OW_F1 + (((size_t)nt * 4 + kc) << 9) + lane * 8);
        acc[i] = MFMA(a0, b, acc[i], 0, 0, 0);
        acc[2 + i] = MFMA(a1, b, acc[2 + i], 0, 0, 0);
      }
    }
  }
  __syncthreads();  // BAR1a
  if (wv < 4) {
    #pragma unroll
    for (int mt = 0; mt < 2; ++mt)
      #pragma unroll
      for (int i = 0; i < 3; ++i) {
        int up = (wv * 3 + i) * 16 + l15;
        #pragma unroll
        for (int j = 0; j < 4; ++j)
          stb(VA(2), mt * 16 + q4 + j, 384, up * 2, f2bf(acc[mt * 3 + i][j]));
      }
  } else if (wv < 6) {
    #pragma unroll
    for (int i = 0; i < 4; ++i) {
      int u = ((wv - 4) * 4 + i) * 16 + l15;
      float bias = bpre0[u];
      #pragma unroll
      for (int mt = 0; mt < 2; ++mt)
        #pragma unroll
        for (int j = 0; j < 4; ++j)
          stb(SA(2), mt * 16 + q4 + j, 256, u * 2, f2bf(acc[mt * 4 + i][j] + bias));
    }
  } else {
    #pragma unroll
    for (int i = 0; i < 2; ++i) {
      int u = ((wv - 6) * 2 + i) * 16 + l15;
      float bias = bf1[u];
      #pragma unroll
      for (int mt = 0; mt < 2; ++mt)
        #pragma unroll
        for (int j = 0; j < 4; ++j)
          stb(hB, mt * 16 + q4 + j, 128, u * 2, f2bf(siluf_(acc[mt * 2 + i][j] + bias)));
    }
  }
  __syncthreads();  // BAR1b

  // ---- P1.5: svh[e][K] = sum_m v_in[e,K,m]*sh1[m] -> elB (K<128) / t1B (K>=128) ----
  for (int o = t; o < 32 * 192; o += 512) {
    int e = o / 192, K = o % 192;
    int src = K >> 6, kk = K & 63;
    const char* vb = VA(src);
    float x0 = bf2f(ldbs(vb, e, 384, (3 * kk + 0) * 2));
    float x1 = bf2f(ldbs(vb, e, 384, (3 * kk + 1) * 2));
    float x2 = bf2f(ldbs(vb, e, 384, (3 * kk + 2) * 2));
    float sv = x0 * shF[e * 4 + 1] + x1 * shF[e * 4 + 2] + x2 * shF[e * 4 + 3];
    if (K < 128) stb(elB, e, 256, K * 2, f2bf(sv));
    else stb(t1B, e, 128, (K - 128) * 2, f2bf(sv));
  }
  __syncthreads();  // BAR1c

  // ---- P2: out_s (w0-5, acc4) | t1 (w6-7, acc4) ; h2 (all, acc1) ----
  f32x4 os[4] = {F4Z, F4Z, F4Z, F4Z};
  f32x4 h2a = F4Z;
  {
    const int hmt = wv >> 2, hnt = wv & 3;
    #pragma unroll
    for (int kc = 0; kc < 2; ++kc) {
      bf16x8 a = ldb8(hB, hmt * 16 + l15, 128, kc * 64 + cbl);
      bf16x8 b = *(const bf16x8*)(wbf + OW_F2 + (((size_t)hnt * 2 + kc) << 9) + lane * 8);
      h2a = MFMA(a, b, h2a, 0, 0, 0);
    }
  }
  if (wv < 6) {
    for (int kc = 0; kc < 12; ++kc) {
      int buf = kc >> 2, cB = (kc & 3) * 64 + cbl;
      bf16x8 a0 = ldb8(SA(buf), l15, 256, cB);
      bf16x8 a1 = ldb8(SA(buf), 16 + l15, 256, cB);
      #pragma unroll
      for (int i = 0; i < 2; ++i) {
        int nt = wv * 2 + i;
        bf16x8 b = *(const bf16x8*)(wbf + OW_SS + (((size_t)nt * 12 + kc) << 9) + lane * 8);
        os[i] = MFMA(a0, b, os[i], 0, 0, 0);
        os[2 + i] = MFMA(a1, b, os[2 + i], 0, 0, 0);
      }
    }
    #pragma unroll
    for (int mt = 0; mt < 2; ++mt)
      #pragma unroll
      for (int i = 0; i < 2; ++i)
        #pragma unroll
        for (int j = 0; j < 4; ++j)
          os[mt * 2 + i][j] *= shF[(mt * 16 + q4 + j) * 4 + 0];
    for (int kc = 0; kc < 6; ++kc) {
      const char* sb_ = (kc < 4) ? elB : t1B;
      int rB = (kc < 4) ? 256 : 128;
      int cB = ((kc < 4) ? kc : (kc - 4)) * 64 + cbl;
      bf16x8 a0 = ldb8(sb_, l15, rB, cB);
      bf16x8 a1 = ldb8(sb_, 16 + l15, rB, cB);
      #pragma unroll
      for (int i = 0; i < 2; ++i) {
        int nt = wv * 2 + i;
        bf16x8 b = *(const bf16x8*)(wbf + OW_VS + (((size_t)nt * 6 + kc) << 9) + lane * 8);
        os[i] = MFMA(a0, b, os[i], 0, 0, 0);
        os[2 + i] = MFMA(a1, b, os[2 + i], 0, 0, 0);
      }
    }
  } else {
    for (int kc = 0; kc < 12; ++kc) {
      int buf = kc >> 2, cB = (kc & 3) * 64 + cbl;
      bf16x8 a0 = ldb8(SA(buf), l15, 256, cB);
      bf16x8 a1 = ldb8(SA(buf), 16 + l15, 256, cB);
      #pragma unroll
      for (int i = 0; i < 2; ++i) {
        int nt = (wv - 6) * 2 + i;
        bf16x8 b = *(const bf16x8*)(wbf + OW_SV + (((size_t)nt * 12 + kc) << 9) + lane * 8);
        os[i] = MFMA(a0, b, os[i], 0, 0, 0);
        os[2 + i] = MFMA(a1, b, os[2 + i], 0, 0, 0);
      }
    }
  }
  __syncthreads();  // BAR2a
  {
    const int hmt = wv >> 2;
    int u = (wv & 3) * 16 + l15;
    float bias = bf2[u];
    #pragma unroll
    for (int j = 0; j < 4; ++j)
      stb(hB, hmt * 16 + q4 + j, 128, u * 2, f2bf(siluf_(h2a[j] + bias)));
  }
  if (wv >= 6) {
    #pragma unroll
    for (int mt = 0; mt < 2; ++mt)
      #pragma unroll
      for (int i = 0; i < 2; ++i) {
        int u = ((wv - 6) * 2 + i) * 16 + l15;
        #pragma unroll
        for (int j = 0; j < 4; ++j)
          stb(t1B, mt * 16 + q4 + j, 128, u * 2, f2bf(os[mt * 2 + i][j]));
      }
  }
  __syncthreads();  // BAR2b

  // ---- P3: w = h2@Wf3 + bf3 ----
  {
    f32x4 wa[3] = {F4Z, F4Z, F4Z};
    const int mtw = wv >> 2;
    #pragma unroll
    for (int kc = 0; kc < 2; ++kc) {
      bf16x8 a = ldb8(hB, mtw * 16 + l15, 128, kc * 64 + cbl);
      #pragma unroll
      for (int i = 0; i < 3; ++i) {
        int nt = (wv & 3) * 3 + i;
        bf16x8 b = *(const bf16x8*)(wbf + OW_F3 + (((size_t)nt * 2 + kc) << 9) + lane * 8);
        wa[i] = MFMA(a, b, wa[i], 0, 0, 0);
      }
    }
    #pragma unroll
    for (int i = 0; i < 3; ++i) {
      int up = ((wv & 3) * 3 + i) * 16 + l15;
      float bias = bf3[up];
      #pragma unroll
      for (int j = 0; j < 4; ++j)
        stb(wB, mtw * 16 + q4 + j, 384, up * 2, f2bf(wa[i][j] + bias));
    }
  }
  __syncthreads();  // BAR3

  // ---- P4: gating (w0-5) + out_v MFMAs (all) ----
  if (wv < 6) {
    #pragma unroll
    for (int mt = 0; mt < 2; ++mt)
      #pragma unroll
      for (int i = 0; i < 2; ++i) {
        int up = (wv * 2 + i) * 16 + l15;
        #pragma unroll
        for (int j = 0; j < 4; ++j) {
          int e = mt * 16 + q4 + j;
          float w_ = bf2f(ldbs(wB, e, 384, up * 2));
          float o_ = os[mt * 2 + i][j];
          if (up < 128) stb(zsB, e, 256, up * 2, f2bf(siluf_(o_) * w_));
          else stb(gateB, e, 128, (up - 128) * 2, f2bf(sigmoidf_(o_) * w_));
        }
      }
  }
  f32x4 ov[3] = {F4Z, F4Z, F4Z};
  {
    const int mtv = wv >> 2;
    for (int p = 0; p < 3; ++p)
      for (int kc6 = 0; kc6 < 6; ++kc6) {
        int cB = kc6 * 64 + cbl;
        bf16x8 a = ldb8(VA(p), mtv * 16 + l15, 384, cB);
        int kcg = p * 6 + kc6;
        #pragma unroll
        for (int i = 0; i < 3; ++i) {
          int nt = (wv & 3) * 3 + i;
          bf16x8 b = *(const bf16x8*)(wbf + OW_VVX + (((size_t)nt * 18 + kcg) << 9) + lane * 8);
          ov[i] = MFMA(a, b, ov[i], 0, 0, 0);
        }
      }
  }
  __syncthreads();  // BAR4
  {
    const int mtv = wv >> 2;
    #pragma unroll
    for (int i = 0; i < 3; ++i) {
      int up = ((wv & 3) * 3 + i) * 16 + l15;
      int u = (up * 683) >> 11, m = up - 3 * u;
      #pragma unroll
      for (int j = 0; j < 4; ++j) {
        int e = mtv * 16 + q4 + j;
        float t1v = bf2f(ldbs(t1B, e, 128, u * 2));
        float g = bf2f(ldbs(gateB, e, 128, u * 2));
        float val = ov[i][j] * shF[e * 4 + 0] + t1v * shF[e * 4 + 1 + m];
        stb(zvB, e, 384, up * 2, f2bf(val * g));
      }
    }
  }
  __syncthreads();  // BAR5

  // ---- P5: post0 + post1, RMW onto sc in d_out + per-edge stats ----
  {
    f32x4 p0[2] = {F4Z, F4Z};
    #pragma unroll
    for (int kc = 0; kc < 4; ++kc) {
      int cB = kc * 64 + cbl;
      bf16x8 a0 = ldb8(zsB, l15, 256, cB);
      bf16x8 a1 = ldb8(zsB, 16 + l15, 256, cB);
      bf16x8 b = *(const bf16x8*)(wbf + OW_P0 + (((size_t)wv * 4 + kc) << 9) + lane * 8);
      p0[0] = MFMA(a0, b, p0[0], 0, 0, 0);
      p0[1] = MFMA(a1, b, p0[1], 0, 0, 0);
    }
    int u = wv * 16 + l15;
    float bias = bpost0[u];
    float s1p[8], s2p[8];
    #pragma unroll
    for (int mt = 0; mt < 2; ++mt)
      #pragma unroll
      for (int j = 0; j < 4; ++j) {
        size_t o = (size_t)(e0 + mt * 16 + q4 + j) * DIM + u;
        float z = out[o] + p0[mt][j] + bias;
        out[o] = z;
        s1p[mt * 4 + j] = z;
        s2p[mt * 4 + j] = z * z;
      }
    #pragma unroll
    for (int msk = 1; msk < 16; msk <<= 1)
      #pragma unroll
      for (int k = 0; k < 8; ++k) {
        s1p[k] += __shfl_xor(s1p[k], msk);
        s2p[k] += __shfl_xor(s2p[k], msk);
      }
    if (l15 == 0) {
      #pragma unroll
      for (int mt = 0; mt < 2; ++mt)
        #pragma unroll
        for (int j = 0; j < 4; ++j) {
          int e = mt * 16 + q4 + j;
          atomicAdd(&sS[e], s1p[mt * 4 + j]);
          atomicAdd(&sS2[e], s2p[mt * 4 + j]);
        }
    }
  }
  {
    f32x4 p1[3] = {F4Z, F4Z, F4Z};
    const int mtv = wv >> 2;
    #pragma unroll
    for (int kc = 0; kc < 6; ++kc) {
      int cB = kc * 64 + cbl;
      bf16x8 a = ldb8(zvB, mtv * 16 + l15, 384, cB);
      #pragma unroll
      for (int i = 0; i < 3; ++i) {
        int nt = (wv & 3) * 3 + i;
        bf16x8 b = *(const bf16x8*)(wbf + OW_P1X + (((size_t)nt * 6 + kc) << 9) + lane * 8);
        p1[i] = MFMA(a, b, p1[i], 0, 0, 0);
      }
    }
    float svp[4] = {0.f, 0.f, 0.f, 0.f};
    #pragma unroll
    for (int i = 0; i < 3; ++i) {
      int up = ((wv & 3) * 3 + i) * 16 + l15;
      #pragma unroll
      for (int j = 0; j < 4; ++j) {
        size_t o = (size_t)(e0 + mtv * 16 + q4 + j) * DIM + 128 + up;
        float z = out[o] + p1[i][j];
        out[o] = z;
        svp[j] += z * z;
      }
    }
    #pragma unroll
    for (int msk = 1; msk < 16; msk <<= 1)
      #pragma unroll
      for (int j = 0; j < 4; ++j) svp[j] += __shfl_xor(svp[j], msk);
    if (l15 == 0) {
      #pragma unroll
      for (int j = 0; j < 4; ++j)
        atomicAdd(&sV[mtv * 16 + q4 + j], svp[j]);
    }
  }
  __syncthreads();  // BAR6
  if (t < 32) {
    int g = batch[ijL[t]];
    float* sb = statsB + ((size_t)(blockIdx.x & 63)) * 64 + g * 4;
    atomicAdd(sb + 0, 1.0f);
    atomicAdd(sb + 1, sS[t]);
    atomicAdd(sb + 2, sS2[t]);
    atomicAdd(sb + 3, sV[t]);
  }
#undef SA
#undef VA
}

// ---------------- K4: normalize + residual (float4; reduces 64 stat buckets) ----------------
__global__ __launch_bounds__(256) void k_norm(
    const float* __restrict__ edge_fea, const int* __restrict__ eidx,
    const int* __restrict__ batch, const float* __restrict__ stats,
    const float* __restrict__ gamma_s, const float* __restrict__ beta_s,
    const float* __restrict__ gamma_v, float* __restrict__ out) {
  __shared__ float meanL[16], invsL[16], invvL[16];
  __shared__ int gL[16];
  const int t = threadIdx.x;
  const int e0 = blockIdx.x * 16;
  if (t < 16) {
    float c = 0.f, a = 0.f, b = 0.f, d = 0.f;
    for (int q = 0; q < 64; ++q) {
      const float* p = stats + (size_t)q * 64 + t * 4;
      c += p[0]; a += p[1]; b += p[2]; d += p[3];
    }
    float cnt = fmaxf(c, 1.0f);
    float m = a / (cnt * 128.0f);
    float var = b / (cnt * 128.0f) - m * m;
    meanL[t] = m;
    invsL[t] = rsqrtf(var + 1e-5f);
    invvL[t] = rsqrtf(d / (cnt * 192.0f) + 1e-5f);
  }
  if (t >= 32 && t < 48) gL[t - 32] = batch[eidx[e0 + t - 32]];
  __syncthreads();
  for (int o = t; o < 16 * 80; o += 256) {
    int e = o / 80, q = o % 80;
    size_t idx = (size_t)(e0 + e) * 80 + q;
    float4 z = ((const float4*)out)[idx];
    float4 ef = ((const float4*)edge_fea)[idx];
    int g = gL[e];
    float4 r;
    if (q < 32) {
      int c = q * 4;
      r.x = (z.x - meanL[g]) * invsL[g] * gamma_s[c + 0] + beta_s[c + 0] + ef.x;
      r.y = (z.y - meanL[g]) * invsL[g] * gamma_s[c + 1] + beta_s[c + 1] + ef.y;
      r.z = (z.z - meanL[g]) * invsL[g] * gamma_s[c + 2] + beta_s[c + 2] + ef.z;
      r.w = (z.w - meanL[g]) * invsL[g] * gamma_s[c + 3] + beta_s[c + 3] + ef.w;
    } else {
      int cc = q * 4 - 128;
      r.x = z.x * invvL[g] * gamma_v[(cc + 0) / 3] + ef.x;
      r.y = z.y * invvL[g] * gamma_v[(cc + 1) / 3] + ef.y;
      r.z = z.z * invvL[g] * gamma_v[(cc + 2) / 3] + ef.z;
      r.w = z.w * invvL[g] * gamma_v[(cc + 3) / 3] + ef.w;
    }
    ((float4*)out)[idx] = r;
  }
}

extern "C" void kernel_launch(void* const* d_in, const int* in_sizes, int n_in,
                              void* d_out, int out_size, void* d_ws, size_t ws_size,
                              hipStream_t stream) {
  const float* node_fea = (const float*)d_in[0];
  const float* edge_oh  = (const float*)d_in[1];
  const float* edge_sh  = (const float*)d_in[2];
  const float* edge_fea = (const float*)d_in[3];
  const float* elen     = (const float*)d_in[4];
  const int*   eidx     = (const int*)d_in[5];
  const int*   batch    = (const int*)d_in[6];
  const float* Wsc_s    = (const float*)d_in[7];
  const float* Wsc_v    = (const float*)d_in[8];
  const float* Wpre0    = (const float*)d_in[9];
  const float* bpre0    = (const float*)d_in[10];
  const float* Wpre1    = (const float*)d_in[11];
  const float* Wss      = (const float*)d_in[12];
  const float* Wvs      = (const float*)d_in[13];
  const float* Wsv      = (const float*)d_in[14];
  const float* Wvv      = (const float*)d_in[15];
  const float* Wf1      = (const float*)d_in[16];
  const float* bf1      = (const float*)d_in[17];
  const float* Wf2      = (const float*)d_in[18];
  const float* bf2      = (const float*)d_in[19];
  const float* Wf3      = (const float*)d_in[20];
  const float* bf3      = (const float*)d_in[21];
  const float* Wpost0   = (const float*)d_in[22];
  const float* bpost0   = (const float*)d_in[23];
  const float* Wpost1   = (const float*)d_in[24];
  const float* gamma_s  = (const float*)d_in[25];
  const float* beta_s   = (const float*)d_in[26];
  const float* gamma_v  = (const float*)d_in[27];
  float* out = (float*)d_out;

  char* ws = (char*)d_ws;
  float* statsB = (float*)ws;               // [64 buckets][16 g][4]
  u16* wbf = (u16*)(ws + 16384);

  hipMemsetAsync(statsB, 0, 64 * 64 * sizeof(float), stream);
  k_prep<<<(OW_END + 255) / 256, 256, 0, stream>>>(
      Wsc_s, Wsc_v, Wpre0, Wpre1, Wss, Wvs, Wsv, Wvv,
      Wf1, Wf2, Wf3, Wpost0, Wpost1, wbf);
  const int nblk64 = (E_TOT + MEs - 1) / MEs;  // 1563
  k_sc<<<nblk64, 256, 0, stream>>>(edge_fea, edge_oh, wbf + OW_W2S, wbf + OW_BTV, out);
  k_chain<<<E_TOT / 32, 512, 0, stream>>>(node_fea, edge_sh, edge_fea, elen, eidx, batch,
                                          wbf, bpre0, bf1, bf2, bf3, bpost0, out, statsB);
  k_norm<<<E_TOT / 16, 256, 0, stream>>>(edge_fea, eidx, batch, statsB,
                                         gamma_s, beta_s, gamma_v, out);
}